// Round 5
// baseline (585.015 us; speedup 1.0000x reference)
//
#include <hip/hip_runtime.h>

// Problem: B=8, N=1024, D=1024, H=16, HD=64, FF=4096. Tokens M = 8192.
// Inputs f32, OUTPUT f32. Internals bf16, f32 accumulation.
// Round 12: gemm256 v2 (ffn1 only). R4's 8-phase port hit 29% MfmaUtil:
// my added sched_barrier(0)s pinned the scheduler (m141 lesson) and phase
// lockstep serialized LDS-reads vs MFMA. v2 = template-faithful: no
// sched_barriers, partial lgkmcnt(8) in the 12-read phases, lb(512,1).
// qkv reverted to the proven gemm_bt<64> (818 TF). proj/ffn2 BK=128 + XCD
// swizzle, attn/LN/cvt unchanged from R10.

typedef unsigned short ushort_t;
typedef __bf16 bf16x8 __attribute__((ext_vector_type(8)));
typedef float f32x4 __attribute__((ext_vector_type(4)));
typedef unsigned short u16x8 __attribute__((ext_vector_type(8)));

__device__ __forceinline__ void async_ld16(const void* g, void* l) {
  // global -> LDS direct, 16B per lane. LDS dst is wave-uniform base; HW
  // writes base + lane*16.
  __builtin_amdgcn_global_load_lds(
      (void __attribute__((address_space(1)))*)const_cast<void*>(g),
      (void __attribute__((address_space(3)))*)l, 16, 0, 0);
}

__device__ __forceinline__ float bf2f(ushort_t h) {
  union { unsigned int u; float f; } v;
  v.u = ((unsigned int)h) << 16;
  return v.f;
}
__device__ __forceinline__ ushort_t f2bf(float f) {
  union { float f; unsigned int u; } v;
  v.f = f;
  unsigned int r = v.u + 0x7FFFu + ((v.u >> 16) & 1u);  // RNE
  return (ushort_t)(r >> 16);
}
// 2^x via HW v_exp_f32 (D = 2^S0 per ISA); guarded fallback keeps semantics.
__device__ __forceinline__ float fast_exp2(float x) {
#if __has_builtin(__builtin_amdgcn_exp2f)
  return __builtin_amdgcn_exp2f(x);
#else
  return __expf(x * 0.6931471805599453f);
#endif
}
// tanh-form GELU (~3e-4 dev from exact erf; 0.078 threshold headroom)
__device__ __forceinline__ float gelu_f(float x) {
  float y = 0.7978845608028654f * (x + 0.044715f * x * x * x);
  float e = __expf(2.0f * y);
  float t = 1.0f - 2.0f / (e + 1.0f);
  return 0.5f * x * (1.0f + t);
}

// ---------------- f32 -> bf16 weight conversion (8 elems/thread) ------------
__global__ void __launch_bounds__(256) cvt_f32_bf16(const float* __restrict__ src,
                                                    ushort_t* __restrict__ dst, int n) {
  int i = (blockIdx.x * 256 + threadIdx.x) * 8;
  if (i >= n) return;
  float4 a = *(const float4*)(src + i);
  float4 b = *(const float4*)(src + i + 4);
  u16x8 o;
  o[0] = f2bf(a.x); o[1] = f2bf(a.y); o[2] = f2bf(a.z); o[3] = f2bf(a.w);
  o[4] = f2bf(b.x); o[5] = f2bf(b.y); o[6] = f2bf(b.z); o[7] = f2bf(b.w);
  *(u16x8*)(dst + i) = o;
}

// two-buffer variant: one launch for Wqkv (n0) + Wproj (n1), non-aliasing dsts
__global__ void __launch_bounds__(256) cvt_f32_bf16_2(const float* __restrict__ s0,
                                                      ushort_t* __restrict__ d0, int n0,
                                                      const float* __restrict__ s1,
                                                      ushort_t* __restrict__ d1, int n1) {
  int i = (blockIdx.x * 256 + threadIdx.x) * 8;
  const float* src;
  ushort_t* dst;
  if (i < n0) {
    src = s0 + i; dst = d0 + i;
  } else {
    int j = i - n0;
    if (j >= n1) return;
    src = s1 + j; dst = d1 + j;
  }
  float4 a = *(const float4*)(src);
  float4 b = *(const float4*)(src + 4);
  u16x8 o;
  o[0] = f2bf(a.x); o[1] = f2bf(a.y); o[2] = f2bf(a.z); o[3] = f2bf(a.w);
  o[4] = f2bf(b.x); o[5] = f2bf(b.y); o[6] = f2bf(b.z); o[7] = f2bf(b.w);
  *(u16x8*)dst = o;
}

// ---------------- LayerNorm (f32 in, bf16 out): 1 wave per token ------------
__global__ void __launch_bounds__(256) ln_f32(const float* __restrict__ X,
                                              const float* __restrict__ G,
                                              const float* __restrict__ Bb,
                                              ushort_t* __restrict__ Y) {
  int tok = blockIdx.x * 4 + (threadIdx.x >> 6);
  int lane = threadIdx.x & 63;
  const float* xr = X + (size_t)tok * 1024 + lane * 16;
  float v[16];
#pragma unroll
  for (int c = 0; c < 4; c++) {
    float4 a = *(const float4*)(xr + c * 4);
    v[c * 4 + 0] = a.x; v[c * 4 + 1] = a.y; v[c * 4 + 2] = a.z; v[c * 4 + 3] = a.w;
  }
  float s = 0.f, ss = 0.f;
#pragma unroll
  for (int j = 0; j < 16; j++) { s += v[j]; ss += v[j] * v[j]; }
#pragma unroll
  for (int off = 32; off >= 1; off >>= 1) {
    s += __shfl_xor(s, off);
    ss += __shfl_xor(ss, off);
  }
  float mu = s * (1.f / 1024.f);
  float var = ss * (1.f / 1024.f) - mu * mu;
  float rs = rsqrtf(var + 1e-5f);
  u16x8 o0, o1;
#pragma unroll
  for (int c = 0; c < 4; c++) {
    float4 g = *(const float4*)(G + lane * 16 + c * 4);
    float4 bb = *(const float4*)(Bb + lane * 16 + c * 4);
    ushort_t* op = (c < 2) ? (ushort_t*)&o0 : (ushort_t*)&o1;
    int base = (c & 1) * 4;
    op[base + 0] = f2bf((v[c * 4 + 0] - mu) * rs * g.x + bb.x);
    op[base + 1] = f2bf((v[c * 4 + 1] - mu) * rs * g.y + bb.y);
    op[base + 2] = f2bf((v[c * 4 + 2] - mu) * rs * g.z + bb.z);
    op[base + 3] = f2bf((v[c * 4 + 3] - mu) * rs * g.w + bb.w);
  }
  ushort_t* yr = Y + (size_t)tok * 1024 + lane * 16;
  *(u16x8*)yr = o0;
  *(u16x8*)(yr + 8) = o1;
}

// ---------------- LayerNorm (bf16 in, bf16 out): 1 wave per token -----------
__global__ void __launch_bounds__(256) ln_bf16(const ushort_t* __restrict__ X,
                                               const float* __restrict__ G,
                                               const float* __restrict__ Bb,
                                               ushort_t* __restrict__ Y) {
  int tok = blockIdx.x * 4 + (threadIdx.x >> 6);
  int lane = threadIdx.x & 63;
  const ushort_t* xr = X + (size_t)tok * 1024 + lane * 16;
  u16x8 x0 = *(const u16x8*)xr;
  u16x8 x1 = *(const u16x8*)(xr + 8);
  float v[16];
  float s = 0.f, ss = 0.f;
#pragma unroll
  for (int j = 0; j < 8; j++) { v[j] = bf2f(x0[j]); v[8 + j] = bf2f(x1[j]); }
#pragma unroll
  for (int j = 0; j < 16; j++) { s += v[j]; ss += v[j] * v[j]; }
#pragma unroll
  for (int off = 32; off >= 1; off >>= 1) {
    s += __shfl_xor(s, off);
    ss += __shfl_xor(ss, off);
  }
  float mu = s * (1.f / 1024.f);
  float var = ss * (1.f / 1024.f) - mu * mu;
  float rs = rsqrtf(var + 1e-5f);
  u16x8 o0, o1;
#pragma unroll
  for (int c = 0; c < 4; c++) {
    float4 g = *(const float4*)(G + lane * 16 + c * 4);
    float4 bb = *(const float4*)(Bb + lane * 16 + c * 4);
    ushort_t* op = (c < 2) ? (ushort_t*)&o0 : (ushort_t*)&o1;
    int base = (c & 1) * 4;
    op[base + 0] = f2bf((v[c * 4 + 0] - mu) * rs * g.x + bb.x);
    op[base + 1] = f2bf((v[c * 4 + 1] - mu) * rs * g.y + bb.y);
    op[base + 2] = f2bf((v[c * 4 + 2] - mu) * rs * g.z + bb.z);
    op[base + 3] = f2bf((v[c * 4 + 3] - mu) * rs * g.w + bb.w);
  }
  ushort_t* yr = Y + (size_t)tok * 1024 + lane * 16;
  *(u16x8*)yr = o0;
  *(u16x8*)(yr + 8) = o1;
}

// ---------------- 256x256 8-phase GEMM (K % 128 == 0, M%256==0, N%256==0) ---
// C[M,N] = act(A[M,K] @ B[N,K]^T + bias), bf16 out. 512 thr, 8 waves (2x4),
// per-wave 128x64 out, acc[8][4] 16x16x32 frags. LDS: 2 bufs x [256][64]
// per operand (128 KB). Even K-tiles -> buf0, odd -> buf1 (fixed).
// v2 (R12): template-faithful phase = {ds_read; stage; [lgkmcnt(8) if 12
// reads]; [vmcnt(6) @ ph4/8]; s_barrier; setprio(1) 16 MFMA setprio(0);
// s_barrier}. NO sched_barrier(0) (m141: order-pinning kills scheduling).
// WAR ledger: stages target regions whose last ds_read completed >=1 phase
// earlier (reads complete before each phase's closing barrier, since the
// MFMA consuming them waits lgkmcnt and precedes it). vmcnt(6) at ph4/ph8 =
// 3 half-tiles in flight; each guarantee covers the next 4 phases' reads.
#define MF16 __builtin_amdgcn_mfma_f32_16x16x32_bf16
#define STG_A(BUF, R0, KK) \
  async_ld16(gA + (size_t)((R0) + srow_l) * K + (KK) + scol_l, sA + (BUF)*16384 + ((R0) + ldsrow) * 64)
#define STG_B(BUF, R0, KK) \
  async_ld16(gB + (size_t)((R0) + srow_l) * K + (KK) + scol_l, sB + (BUF)*16384 + ((R0) + ldsrow) * 64)
#define PHASE(MQ, SOFF, READB, STAGE_STMT, DO_VM)                                                    \
  {                                                                                                  \
    if (READB) {                                                                                     \
      _Pragma("unroll") for (int ni = 0; ni < 4; ni++) {                                             \
        int br = wc * 64 + ni * 16 + l16;                                                            \
        bfr[ni][0] = *(const bf16x8*)(sB + (SOFF) + br * 64 + ((quad ^ (l16 & 7)) * 8));             \
        bfr[ni][1] = *(const bf16x8*)(sB + (SOFF) + br * 64 + (((4 + quad) ^ (l16 & 7)) * 8));       \
      }                                                                                              \
    }                                                                                                \
    int ar = wr * 128 + (MQ) * 32 + l16;                                                             \
    bf16x8 a00 = *(const bf16x8*)(sA + (SOFF) + ar * 64 + ((quad ^ (l16 & 7)) * 8));                 \
    bf16x8 a01 = *(const bf16x8*)(sA + (SOFF) + ar * 64 + (((4 + quad) ^ (l16 & 7)) * 8));           \
    bf16x8 a10 = *(const bf16x8*)(sA + (SOFF) + (ar + 16) * 64 + ((quad ^ (l16 & 7)) * 8));          \
    bf16x8 a11 = *(const bf16x8*)(sA + (SOFF) + (ar + 16) * 64 + (((4 + quad) ^ (l16 & 7)) * 8));    \
    STAGE_STMT;                                                                                      \
    if (READB) asm volatile("s_waitcnt lgkmcnt(8)" ::: "memory");                                    \
    if (DO_VM) asm volatile("s_waitcnt vmcnt(6)" ::: "memory");                                      \
    __builtin_amdgcn_s_barrier();                                                                    \
    __builtin_amdgcn_s_setprio(1);                                                                   \
    _Pragma("unroll") for (int ni = 0; ni < 4; ni++) {                                               \
      acc[(MQ)*2 + 0][ni] = MF16(a00, bfr[ni][0], acc[(MQ)*2 + 0][ni], 0, 0, 0);                     \
      acc[(MQ)*2 + 0][ni] = MF16(a01, bfr[ni][1], acc[(MQ)*2 + 0][ni], 0, 0, 0);                     \
      acc[(MQ)*2 + 1][ni] = MF16(a10, bfr[ni][0], acc[(MQ)*2 + 1][ni], 0, 0, 0);                     \
      acc[(MQ)*2 + 1][ni] = MF16(a11, bfr[ni][1], acc[(MQ)*2 + 1][ni], 0, 0, 0);                     \
    }                                                                                                \
    __builtin_amdgcn_s_setprio(0);                                                                   \
    __builtin_amdgcn_s_barrier();                                                                    \
  }

__global__ void __launch_bounds__(512, 1)
gemm256_bt(const ushort_t* __restrict__ A, const ushort_t* __restrict__ Bw,
           const float* __restrict__ bias, ushort_t* __restrict__ Cb,
           int M, int N, int K, int act) {
  __shared__ __align__(16) ushort_t sA[2 * 256 * 64];  // 64 KB
  __shared__ __align__(16) ushort_t sB[2 * 256 * 64];  // 64 KB
  int t = threadIdx.x;
  int wid = t >> 6, lane = t & 63;
  int quad = lane >> 4, l16 = lane & 15;
  int wr = wid >> 2, wc = wid & 3;  // 2 x 4 wave grid
  int m0 = blockIdx.y * 256, n0 = blockIdx.x * 256;

  // staging lane geometry: per chunk (64 rows x 64 cols), wave wid covers
  // rows wid*8..wid*8+7; lane -> row wid*8+(lane>>3), slot lane&7; source
  // granule = slot ^ (row&7).
  int srow_l = wid * 8 + (lane >> 3);
  int scol_l = ((lane & 7) ^ ((lane >> 3) & 7)) * 8;
  int ldsrow = wid * 8;
  const ushort_t* gA = A + (size_t)m0 * K;
  const ushort_t* gB = Bw + (size_t)n0 * K;

  f32x4 zero = {0.f, 0.f, 0.f, 0.f};
  f32x4 acc[8][4];
#pragma unroll
  for (int i = 0; i < 8; i++)
#pragma unroll
    for (int j = 0; j < 4; j++) acc[i][j] = zero;
  bf16x8 bfr[4][2];

  int NT = K >> 6;       // K-tiles (16 for K=1024)
  int NITER = NT >> 1;   // 8

  // prologue: K0 -> buf0 (8 loads, oldest first), K1 -> buf1 (B + A-H0)
  STG_B(0, 0, 0);  STG_B(0, 64, 0);  STG_B(0, 128, 0); STG_B(0, 192, 0);
  STG_A(0, 0, 0);  STG_A(0, 128, 0); STG_A(0, 64, 0);  STG_A(0, 192, 0);
  STG_B(1, 0, 64); STG_B(1, 64, 64); STG_B(1, 128, 64); STG_B(1, 192, 64);
  STG_A(1, 0, 64); STG_A(1, 128, 64);
  asm volatile("s_waitcnt vmcnt(6)" ::: "memory");  // K0 landed, K1 in flight
  __builtin_amdgcn_s_barrier();

  // main: iterations 0..NITER-2 (K-tiles 2i,2i+1); stages 2i+2,2i+3 + A(2i+1)H1
  for (int i = 0; i < NITER - 1; ++i) {
    int kk1 = (2 * i + 1) << 6;
    int kk2 = (2 * i + 2) << 6;
    int kk3 = (2 * i + 3) << 6;
    PHASE(0, 0,     true,  { STG_A(1, 64, kk1);  STG_A(1, 192, kk1); }, false)
    PHASE(1, 0,     false, { STG_B(0, 0, kk2);   STG_B(0, 64, kk2);  }, false)
    PHASE(2, 0,     false, { STG_B(0, 128, kk2); STG_B(0, 192, kk2); }, false)
    PHASE(3, 0,     false, { STG_A(0, 0, kk2);   STG_A(0, 128, kk2); }, true)
    PHASE(0, 16384, true,  { STG_A(0, 64, kk2);  STG_A(0, 192, kk2); }, false)
    PHASE(1, 16384, false, { STG_B(1, 0, kk3);   STG_B(1, 64, kk3);  }, false)
    PHASE(2, 16384, false, { STG_B(1, 128, kk3); STG_B(1, 192, kk3); }, false)
    PHASE(3, 16384, false, { STG_A(1, 0, kk3);   STG_A(1, 128, kk3); }, true)
  }

  // tail: finish staging K(NT-1) A-H1, drain, compute last two K-tiles
  {
    int kkL = (NT - 1) << 6;
    STG_A(1, 64, kkL); STG_A(1, 192, kkL);
    asm volatile("s_waitcnt vmcnt(0)" ::: "memory");
    __builtin_amdgcn_s_barrier();
    PHASE(0, 0,     true,  {}, false)
    PHASE(1, 0,     false, {}, false)
    PHASE(2, 0,     false, {}, false)
    PHASE(3, 0,     false, {}, false)
    PHASE(0, 16384, true,  {}, false)
    PHASE(1, 16384, false, {}, false)
    PHASE(2, 16384, false, {}, false)
    PHASE(3, 16384, false, {}, false)
  }

  // epilogue: C/D layout row = quad*4+r, col = l16. Per-wave LDS repack
  // (eb aliases sA buf0; all LDS reads done + no loads in flight).
  float bv[4];
#pragma unroll
  for (int ni = 0; ni < 4; ni++) bv[ni] = bias[n0 + wc * 64 + ni * 16 + l16];
  ushort_t* eb = sA + wid * (16 * 72);
  int lr = lane >> 2, lc = (lane & 3) * 8;
#pragma unroll
  for (int mi = 0; mi < 8; mi++) {
    int row = m0 + wr * 128 + mi * 16;
#pragma unroll
    for (int ni = 0; ni < 4; ni++)
#pragma unroll
      for (int r = 0; r < 4; r++) {
        float vv = acc[mi][ni][r] + bv[ni];
        if (act) vv = gelu_f(vv);
        eb[(quad * 4 + r) * 72 + ni * 16 + l16] = f2bf(vv);
      }
#pragma unroll
    for (int hc = 0; hc < 64; hc += 32) {
      u16x8 o = *(const u16x8*)(eb + lr * 72 + hc + lc);
      *(u16x8*)(Cb + (size_t)(row + lr) * N + n0 + wc * 64 + hc + lc) = o;
    }
  }
}

// ---------------- GEMM: C[M,N] = act(A[M,K] @ B[N,K]^T + bias) (+Res) -------
// 128x128 tile, template BK in {64,128}, 4 waves 2x2, 4x4 frags.
template <int BK>
__global__ void __launch_bounds__(256, (BK == 64 ? 4 : 2))
gemm_bt(const ushort_t* __restrict__ A,
        const ushort_t* __restrict__ Bw,
        const float* __restrict__ bias,
        const float* __restrict__ ResF,
        const ushort_t* __restrict__ ResB,
        ushort_t* __restrict__ Cb,
        float* __restrict__ Cf,
        int M, int N, int K, int act, int swz) {
  constexpr int NG = BK / 8;        // granules per row
  constexpr int GM = NG - 1;        // XOR mask
  constexpr int RPP = 2048 / BK;    // rows staged per pass
  constexpr int NP = BK / 16;       // passes per tile
  constexpr int NC = BK / 32;       // k-chunks per K-step
  __shared__ __align__(16) ushort_t sAB[2 * 128 * BK];
  ushort_t* sA = sAB;
  ushort_t* sB = sAB + 128 * BK;
  int t = threadIdx.x;
  int wave = t >> 6, lane = t & 63;
  int quad = lane >> 4, l16 = lane & 15;
  int wm = (wave & 1) * 64, wn = (wave >> 1) * 64;

  int bx = blockIdx.x, by = blockIdx.y;
  if (swz) {
    int lid = by * gridDim.x + bx;
    int xcd = lid & 7, slot = lid >> 3;
    int mchunk = gridDim.y >> 3;           // m-tiles per XCD
    by = xcd * mchunk + slot / gridDim.x;
    bx = slot % gridDim.x;
  }
  int m0 = by * 128, n0 = bx * 128;

  f32x4 zero = {0.f, 0.f, 0.f, 0.f};
  f32x4 acc[4][4];
#pragma unroll
  for (int i = 0; i < 4; i++)
#pragma unroll
    for (int j = 0; j < 4; j++) acc[i][j] = zero;

  int srow = t / NG;
  int scol = ((t & GM) ^ (srow & GM)) * 8;
  const ushort_t* gA = A + (size_t)(m0 + srow) * K + scol;
  const ushort_t* gB = Bw + (size_t)(n0 + srow) * K + scol;

  for (int k0 = 0; k0 < K; k0 += BK) {
#pragma unroll
    for (int p = 0; p < NP; p++) {
      async_ld16(gA + (size_t)p * RPP * K + k0, sA + p * 2048 + wave * 512);
      async_ld16(gB + (size_t)p * RPP * K + k0, sB + p * 2048 + wave * 512);
    }
    __syncthreads();
#pragma unroll
    for (int c = 0; c < NC; c++) {
      int col = (((c * 4 + quad) ^ (l16 & GM)) * 8);
      bf16x8 af[4], bfr[4];
#pragma unroll
      for (int i = 0; i < 4; i++) {
        af[i]  = *(const bf16x8*)(sA + (wm + i * 16 + l16) * BK + col);
        bfr[i] = *(const bf16x8*)(sB + (wn + i * 16 + l16) * BK + col);
      }
#pragma unroll
      for (int mi = 0; mi < 4; mi++)
#pragma unroll
        for (int ni = 0; ni < 4; ni++)
          acc[mi][ni] = __builtin_amdgcn_mfma_f32_16x16x32_bf16(af[mi], bfr[ni], acc[mi][ni], 0, 0, 0);
    }
    __syncthreads();
  }

  float bv[4];
#pragma unroll
  for (int ni = 0; ni < 4; ni++) bv[ni] = bias[n0 + wn + ni * 16 + l16];

  if (Cf) {
#pragma unroll
    for (int mi = 0; mi < 4; mi++) {
      int row = m0 + wm + mi * 16 + quad * 4;
#pragma unroll
      for (int ni = 0; ni < 4; ni++) {
        int col = n0 + wn + ni * 16 + l16;
#pragma unroll
        for (int r = 0; r < 4; r++) {
          size_t idx = (size_t)(row + r) * N + col;
          float vv = acc[mi][ni][r] + bv[ni];
          if (act) vv = gelu_f(vv);
          if (ResB) vv += bf2f(ResB[idx]);
          Cf[idx] = vv;
        }
      }
    }
  } else {
    ushort_t* eb = sAB + wave * (16 * 72);
    int lr = lane >> 2, lc = (lane & 3) * 8;
#pragma unroll
    for (int mi = 0; mi < 4; mi++) {
      int row = m0 + wm + mi * 16;
#pragma unroll
      for (int ni = 0; ni < 4; ni++)
#pragma unroll
        for (int r = 0; r < 4; r++) {
          float vv = acc[mi][ni][r] + bv[ni];
          if (act) vv = gelu_f(vv);
          eb[(quad * 4 + r) * 72 + ni * 16 + l16] = f2bf(vv);
        }
#pragma unroll
      for (int hc = 0; hc < 64; hc += 32) {
        u16x8 o = *(const u16x8*)(eb + lr * 72 + hc + lc);
        size_t gidx = (size_t)(row + lr) * N + n0 + wn + hc + lc;
        if (ResF) {
          float4 ra = *(const float4*)(ResF + gidx);
          float4 rb = *(const float4*)(ResF + gidx + 4);
          u16x8 o2;
          o2[0] = f2bf(bf2f(o[0]) + ra.x); o2[1] = f2bf(bf2f(o[1]) + ra.y);
          o2[2] = f2bf(bf2f(o[2]) + ra.z); o2[3] = f2bf(bf2f(o[3]) + ra.w);
          o2[4] = f2bf(bf2f(o[4]) + rb.x); o2[5] = f2bf(bf2f(o[5]) + rb.y);
          o2[6] = f2bf(bf2f(o[6]) + rb.z); o2[7] = f2bf(bf2f(o[7]) + rb.w);
          *(u16x8*)(Cb + gidx) = o2;
        } else {
          *(u16x8*)(Cb + gidx) = o;
        }
      }
    }
  }
}

// ---------------- V transpose: qkv V-part [token, 64] -> Vt[b,h,64,1024] ----
__global__ void __launch_bounds__(256) vtrans(const ushort_t* __restrict__ qkv,
                                              ushort_t* __restrict__ Vt) {
  __shared__ ushort_t tile[64][72];
  int t = threadIdx.x;
  int bh = blockIdx.y;
  int b = bh >> 4, h = bh & 15;
  int n0 = blockIdx.x * 64;
  int r = t >> 3;
  int c8 = (t & 7) * 8;
  const ushort_t* src = qkv + ((size_t)(b * 1024 + n0)) * 3072 + 2048 + h * 64;
#pragma unroll
  for (int rr = r; rr < 64; rr += 32) {
    u16x8 d = *(const u16x8*)(src + (size_t)rr * 3072 + c8);
#pragma unroll
    for (int j = 0; j < 8; j++) tile[rr][c8 + j] = d[j];
  }
  __syncthreads();
#pragma unroll
  for (int hh = r; hh < 64; hh += 32) {
    u16x8 o;
#pragma unroll
    for (int j = 0; j < 8; j++) o[j] = tile[c8 + j][hh];
    *(u16x8*)(Vt + ((size_t)bh * 64 + hh) * 1024 + n0 + c8) = o;
  }
}

// ---------------- Flash attention, S^T formulation (R10 version) ------------
__global__ void __launch_bounds__(256) attn_kernel(const ushort_t* __restrict__ qkv,
                                                   const ushort_t* __restrict__ Vt,
                                                   ushort_t* __restrict__ ctx) {
  __shared__ __align__(16) ushort_t sK[128 * 64];
  __shared__ __align__(16) ushort_t sV[64 * 128];
  __shared__ __align__(16) ushort_t sP[4 * 16 * 152];
  int t = threadIdx.x, wave = t >> 6, lane = t & 63;
  int quad = lane >> 4, l16 = lane & 15;
  int bh = blockIdx.y, b = bh >> 4, h = bh & 15;
  int q0 = blockIdx.x * 64 + wave * 16;
  size_t tokbase = (size_t)b * 1024;
  const float SC2 = 0.18033688011112042f;  // 0.125 * log2(e)

  const ushort_t* qrow = qkv + (tokbase + q0 + l16) * 3072 + h * 64;
  bf16x8 qf0 = *(const bf16x8*)(qrow + quad * 8);
  bf16x8 qf1 = *(const bf16x8*)(qrow + 32 + quad * 8);

  f32x4 zero = {0.f, 0.f, 0.f, 0.f};
  f32x4 O[4];
#pragma unroll
  for (int i = 0; i < 4; i++) O[i] = zero;
  float m2 = -3.0e38f, l = 0.f;

  int kvlK = wave * 32 + (lane >> 3);
  int hdKx = lane & 7;
  ushort_t* pw = sP + wave * (16 * 152);

  for (int kv0 = 0; kv0 < 1024; kv0 += 128) {
#pragma unroll
    for (int j = 0; j < 4; j++) {
      int kvl = kvlK + j * 8;
      int hd = (hdKx ^ (kvl & 7)) * 8;
      async_ld16(qkv + (tokbase + kv0 + kvl) * 3072 + 1024 + h * 64 + hd,
                 sK + wave * 2048 + j * 512);
      int hdv = wave * 16 + j * 4 + (lane >> 4);
      int kvloc = ((lane & 15) ^ (hdv & 15)) * 8;
      async_ld16(Vt + ((size_t)bh * 64 + hdv) * 1024 + kv0 + kvloc,
                 sV + wave * 2048 + j * 512);
    }
    __syncthreads();

    f32x4 st[8];
    __builtin_amdgcn_s_setprio(1);
#pragma unroll
    for (int s = 0; s < 8; s++) {
      bf16x8 kf0 = *(const bf16x8*)(sK + (s * 16 + l16) * 64 + ((quad ^ (l16 & 7)) * 8));
      bf16x8 kf1 = *(const bf16x8*)(sK + (s * 16 + l16) * 64 + (((4 + quad) ^ (l16 & 7)) * 8));
      st[s] = __builtin_amdgcn_mfma_f32_16x16x32_bf16(kf0, qf0, zero, 0, 0, 0);
      st[s] = __builtin_amdgcn_mfma_f32_16x16x32_bf16(kf1, qf1, st[s], 0, 0, 0);
    }
    __builtin_amdgcn_s_setprio(0);
    f32x4 mx4 = st[0];
#pragma unroll
    for (int s = 1; s < 8; s++)
#pragma unroll
      for (int r = 0; r < 4; r++) mx4[r] = fmaxf(mx4[r], st[s][r]);
    float mx = fmaxf(fmaxf(mx4[0], mx4[1]), fmaxf(mx4[2], mx4[3]));
    mx = fmaxf(mx, __shfl_xor(mx, 16));
    mx = fmaxf(mx, __shfl_xor(mx, 32));
    float mx2 = mx * SC2;
    if (!__all(mx2 - m2 <= 8.0f)) {
      float mnew2 = fmaxf(m2, mx2);
      float alpha = fast_exp2(m2 - mnew2);
      m2 = mnew2;
      l *= alpha;
#pragma unroll
      for (int ti = 0; ti < 4; ti++)
#pragma unroll
        for (int r = 0; r < 4; r++) O[ti][r] *= alpha;
    }
    float rs = 0.f;
#pragma unroll
    for (int s = 0; s < 8; s++)
#pragma unroll
      for (int r = 0; r < 4; r++) {
        st[s][r] = fast_exp2(fmaf(st[s][r], SC2, -m2));
        rs += st[s][r];
      }
    rs += __shfl_xor(rs, 16);
    rs += __shfl_xor(rs, 32);
    l += rs;
#pragma unroll
    for (int s = 0; s < 8; s++) {
      uint2 pk;
      pk.x = __builtin_amdgcn_perm(__float_as_uint(st[s][1]), __float_as_uint(st[s][0]), 0x07060302u);
      pk.y = __builtin_amdgcn_perm(__float_as_uint(st[s][3]), __float_as_uint(st[s][2]), 0x07060302u);
      *(uint2*)(pw + l16 * 152 + s * 16 + quad * 4) = pk;
    }
    __builtin_amdgcn_s_setprio(1);
#pragma unroll
    for (int c = 0; c < 4; c++) {
      bf16x8 pf = *(const bf16x8*)(pw + l16 * 152 + c * 32 + quad * 8);
#pragma unroll
      for (int ti = 0; ti < 4; ti++) {
        bf16x8 vf = *(const bf16x8*)(sV + (ti * 16 + l16) * 128 + (((c * 4 + quad) ^ l16) * 8));
        O[ti] = __builtin_amdgcn_mfma_f32_16x16x32_bf16(vf, pf, O[ti], 0, 0, 0);
      }
    }
    __builtin_amdgcn_s_setprio(0);
    __syncthreads();
  }
  float inv = 1.0f / l;
  ushort_t* cb = ctx + (tokbase + q0 + l16) * 1024 + h * 64;
#pragma unroll
  for (int ti = 0; ti < 4; ti++) {
    uint2 pk;
    pk.x = (unsigned int)f2bf(O[ti][0] * inv) | ((unsigned int)f2bf(O[ti][1] * inv) << 16);
    pk.y = (unsigned int)f2bf(O[ti][2] * inv) | ((unsigned int)f2bf(O[ti][3] * inv) << 16);
    *(uint2*)(cb + ti * 16 + quad * 4) = pk;
  }
}

extern "C" void kernel_launch(void* const* d_in, const int* in_sizes, int n_in,
                              void* d_out, int out_size, void* d_ws, size_t ws_size,
                              hipStream_t stream) {
  (void)in_sizes; (void)n_in; (void)out_size; (void)ws_size;
  const float* x     = (const float*)d_in[0];
  const float* ln1g  = (const float*)d_in[1];
  const float* ln1b  = (const float*)d_in[2];
  const float* ln2g  = (const float*)d_in[3];
  const float* ln2b  = (const float*)d_in[4];
  const float* Wqkv  = (const float*)d_in[5];
  const float* bqkv  = (const float*)d_in[6];
  const float* Wproj = (const float*)d_in[7];
  const float* bproj = (const float*)d_in[8];
  const float* W1    = (const float*)d_in[9];
  const float* b1    = (const float*)d_in[10];
  const float* W2    = (const float*)d_in[11];
  const float* b2    = (const float*)d_in[12];
  float* out = (float*)d_out;
  char* ws = (char*)d_ws;
  const size_t MB = 1u << 20;
  ushort_t* Wqkv_b  = (ushort_t*)(ws + 0);
  ushort_t* Wproj_b = (ushort_t*)(ws + 6 * MB);
  ushort_t* h1      = (ushort_t*)(ws + 8 * MB);
  ushort_t* qkv     = (ushort_t*)(ws + 24 * MB);
  ushort_t* Vt      = (ushort_t*)(ws + 72 * MB);
  ushort_t* ctx     = (ushort_t*)(ws + 8 * MB);
  ushort_t* out1    = (ushort_t*)(ws + 24 * MB);
  ushort_t* W1_b    = (ushort_t*)(ws + 0);
  ushort_t* h2      = (ushort_t*)(ws + 8 * MB);
  ushort_t* ff1     = (ushort_t*)(ws + 40 * MB);
  ushort_t* W2_b    = (ushort_t*)(ws + 0);

  cvt_f32_bf16_2<<<2048, 256, 0, stream>>>(Wqkv, Wqkv_b, 3 * 1024 * 1024,
                                           Wproj, Wproj_b, 1024 * 1024);
  ln_f32<<<2048, 256, 0, stream>>>(x, ln1g, ln1b, h1);
  gemm_bt<64><<<dim3(24, 64), 256, 0, stream>>>(h1, Wqkv_b, bqkv, nullptr, nullptr, qkv, nullptr, 8192, 3072, 1024, 0, 0);
  vtrans<<<dim3(16, 128), 256, 0, stream>>>(qkv, Vt);
  attn_kernel<<<dim3(16, 128), 256, 0, stream>>>(qkv, Vt, ctx);
  gemm_bt<128><<<dim3(8, 64), 256, 0, stream>>>(ctx, Wproj_b, bproj, x, nullptr, out1, nullptr, 8192, 1024, 1024, 0, 0);
  cvt_f32_bf16<<<2048, 256, 0, stream>>>(W1, W1_b, 4 * 1024 * 1024);
  ln_bf16<<<2048, 256, 0, stream>>>(out1, ln2g, ln2b, h2);
  gemm256_bt<<<dim3(16, 32), 512, 0, stream>>>(h2, W1_b, b1, ff1, 8192, 4096, 1024, 1);
  cvt_f32_bf16<<<2048, 256, 0, stream>>>(W2, W2_b, 4 * 1024 * 1024);
  gemm_bt<128><<<dim3(8, 64), 256, 0, stream>>>(ff1, W2_b, b2, nullptr, out1, nullptr, out, 8192, 1024, 4096, 1, 1);
}

// Round 6
// 486.394 us; speedup vs baseline: 1.2028x; 1.2028x over previous
//
#include <hip/hip_runtime.h>

// Problem: B=8, N=1024, D=1024, H=16, HD=64, FF=4096. Tokens M = 8192.
// Inputs f32, OUTPUT f32. Internals bf16, f32 accumulation.
// Round 13: abandon 8-phase port (two failed attempts: 29%/19% MfmaUtil vs
// 36% for the plain 2-barrier kernel; m232's open quadrant reproduced).
// ffn1 reverted to gemm_bt<64> (proven 84us/818TF). NEW: qkv GEMM fuses the
// V transpose into its epilogue (V-region blocks write Vt[b,h,hd,tok]
// directly via per-wave LDS transpose, stride-74 anti-bank); vtrans kernel
// deleted (-16MB read -16MB write -1 launch). Rest = R10/R3 best config:
// proj/ffn2 BK=128 (ffn2 +XCD swizzle), attn exp2+defer-max+setprio.

typedef unsigned short ushort_t;
typedef __bf16 bf16x8 __attribute__((ext_vector_type(8)));
typedef float f32x4 __attribute__((ext_vector_type(4)));
typedef unsigned short u16x8 __attribute__((ext_vector_type(8)));

__device__ __forceinline__ void async_ld16(const void* g, void* l) {
  // global -> LDS direct, 16B per lane. LDS dst is wave-uniform base; HW
  // writes base + lane*16.
  __builtin_amdgcn_global_load_lds(
      (void __attribute__((address_space(1)))*)const_cast<void*>(g),
      (void __attribute__((address_space(3)))*)l, 16, 0, 0);
}

__device__ __forceinline__ float bf2f(ushort_t h) {
  union { unsigned int u; float f; } v;
  v.u = ((unsigned int)h) << 16;
  return v.f;
}
__device__ __forceinline__ ushort_t f2bf(float f) {
  union { float f; unsigned int u; } v;
  v.f = f;
  unsigned int r = v.u + 0x7FFFu + ((v.u >> 16) & 1u);  // RNE
  return (ushort_t)(r >> 16);
}
// 2^x via HW v_exp_f32 (D = 2^S0 per ISA); guarded fallback keeps semantics.
__device__ __forceinline__ float fast_exp2(float x) {
#if __has_builtin(__builtin_amdgcn_exp2f)
  return __builtin_amdgcn_exp2f(x);
#else
  return __expf(x * 0.6931471805599453f);
#endif
}
// tanh-form GELU (~3e-4 dev from exact erf; 0.078 threshold headroom)
__device__ __forceinline__ float gelu_f(float x) {
  float y = 0.7978845608028654f * (x + 0.044715f * x * x * x);
  float e = __expf(2.0f * y);
  float t = 1.0f - 2.0f / (e + 1.0f);
  return 0.5f * x * (1.0f + t);
}

// ---------------- f32 -> bf16 weight conversion (8 elems/thread) ------------
__global__ void __launch_bounds__(256) cvt_f32_bf16(const float* __restrict__ src,
                                                    ushort_t* __restrict__ dst, int n) {
  int i = (blockIdx.x * 256 + threadIdx.x) * 8;
  if (i >= n) return;
  float4 a = *(const float4*)(src + i);
  float4 b = *(const float4*)(src + i + 4);
  u16x8 o;
  o[0] = f2bf(a.x); o[1] = f2bf(a.y); o[2] = f2bf(a.z); o[3] = f2bf(a.w);
  o[4] = f2bf(b.x); o[5] = f2bf(b.y); o[6] = f2bf(b.z); o[7] = f2bf(b.w);
  *(u16x8*)(dst + i) = o;
}

// two-buffer variant: one launch for Wqkv (n0) + Wproj (n1), non-aliasing dsts
__global__ void __launch_bounds__(256) cvt_f32_bf16_2(const float* __restrict__ s0,
                                                      ushort_t* __restrict__ d0, int n0,
                                                      const float* __restrict__ s1,
                                                      ushort_t* __restrict__ d1, int n1) {
  int i = (blockIdx.x * 256 + threadIdx.x) * 8;
  const float* src;
  ushort_t* dst;
  if (i < n0) {
    src = s0 + i; dst = d0 + i;
  } else {
    int j = i - n0;
    if (j >= n1) return;
    src = s1 + j; dst = d1 + j;
  }
  float4 a = *(const float4*)(src);
  float4 b = *(const float4*)(src + 4);
  u16x8 o;
  o[0] = f2bf(a.x); o[1] = f2bf(a.y); o[2] = f2bf(a.z); o[3] = f2bf(a.w);
  o[4] = f2bf(b.x); o[5] = f2bf(b.y); o[6] = f2bf(b.z); o[7] = f2bf(b.w);
  *(u16x8*)dst = o;
}

// ---------------- LayerNorm (f32 in, bf16 out): 1 wave per token ------------
__global__ void __launch_bounds__(256) ln_f32(const float* __restrict__ X,
                                              const float* __restrict__ G,
                                              const float* __restrict__ Bb,
                                              ushort_t* __restrict__ Y) {
  int tok = blockIdx.x * 4 + (threadIdx.x >> 6);
  int lane = threadIdx.x & 63;
  const float* xr = X + (size_t)tok * 1024 + lane * 16;
  float v[16];
#pragma unroll
  for (int c = 0; c < 4; c++) {
    float4 a = *(const float4*)(xr + c * 4);
    v[c * 4 + 0] = a.x; v[c * 4 + 1] = a.y; v[c * 4 + 2] = a.z; v[c * 4 + 3] = a.w;
  }
  float s = 0.f, ss = 0.f;
#pragma unroll
  for (int j = 0; j < 16; j++) { s += v[j]; ss += v[j] * v[j]; }
#pragma unroll
  for (int off = 32; off >= 1; off >>= 1) {
    s += __shfl_xor(s, off);
    ss += __shfl_xor(ss, off);
  }
  float mu = s * (1.f / 1024.f);
  float var = ss * (1.f / 1024.f) - mu * mu;
  float rs = rsqrtf(var + 1e-5f);
  u16x8 o0, o1;
#pragma unroll
  for (int c = 0; c < 4; c++) {
    float4 g = *(const float4*)(G + lane * 16 + c * 4);
    float4 bb = *(const float4*)(Bb + lane * 16 + c * 4);
    ushort_t* op = (c < 2) ? (ushort_t*)&o0 : (ushort_t*)&o1;
    int base = (c & 1) * 4;
    op[base + 0] = f2bf((v[c * 4 + 0] - mu) * rs * g.x + bb.x);
    op[base + 1] = f2bf((v[c * 4 + 1] - mu) * rs * g.y + bb.y);
    op[base + 2] = f2bf((v[c * 4 + 2] - mu) * rs * g.z + bb.z);
    op[base + 3] = f2bf((v[c * 4 + 3] - mu) * rs * g.w + bb.w);
  }
  ushort_t* yr = Y + (size_t)tok * 1024 + lane * 16;
  *(u16x8*)yr = o0;
  *(u16x8*)(yr + 8) = o1;
}

// ---------------- LayerNorm (bf16 in, bf16 out): 1 wave per token -----------
__global__ void __launch_bounds__(256) ln_bf16(const ushort_t* __restrict__ X,
                                               const float* __restrict__ G,
                                               const float* __restrict__ Bb,
                                               ushort_t* __restrict__ Y) {
  int tok = blockIdx.x * 4 + (threadIdx.x >> 6);
  int lane = threadIdx.x & 63;
  const ushort_t* xr = X + (size_t)tok * 1024 + lane * 16;
  u16x8 x0 = *(const u16x8*)xr;
  u16x8 x1 = *(const u16x8*)(xr + 8);
  float v[16];
  float s = 0.f, ss = 0.f;
#pragma unroll
  for (int j = 0; j < 8; j++) { v[j] = bf2f(x0[j]); v[8 + j] = bf2f(x1[j]); }
#pragma unroll
  for (int j = 0; j < 16; j++) { s += v[j]; ss += v[j] * v[j]; }
#pragma unroll
  for (int off = 32; off >= 1; off >>= 1) {
    s += __shfl_xor(s, off);
    ss += __shfl_xor(ss, off);
  }
  float mu = s * (1.f / 1024.f);
  float var = ss * (1.f / 1024.f) - mu * mu;
  float rs = rsqrtf(var + 1e-5f);
  u16x8 o0, o1;
#pragma unroll
  for (int c = 0; c < 4; c++) {
    float4 g = *(const float4*)(G + lane * 16 + c * 4);
    float4 bb = *(const float4*)(Bb + lane * 16 + c * 4);
    ushort_t* op = (c < 2) ? (ushort_t*)&o0 : (ushort_t*)&o1;
    int base = (c & 1) * 4;
    op[base + 0] = f2bf((v[c * 4 + 0] - mu) * rs * g.x + bb.x);
    op[base + 1] = f2bf((v[c * 4 + 1] - mu) * rs * g.y + bb.y);
    op[base + 2] = f2bf((v[c * 4 + 2] - mu) * rs * g.z + bb.z);
    op[base + 3] = f2bf((v[c * 4 + 3] - mu) * rs * g.w + bb.w);
  }
  ushort_t* yr = Y + (size_t)tok * 1024 + lane * 16;
  *(u16x8*)yr = o0;
  *(u16x8*)(yr + 8) = o1;
}

// ---------------- GEMM: C[M,N] = act(A[M,K] @ B[N,K]^T + bias) (+Res) -------
// 128x128 tile, template BK in {64,128}, 4 waves 2x2, 4x4 frags of 16x16x32
// bf16 MFMA, global_load_lds width=16 staging, K/BK K-iters.
// Tiles: row-major [128][BK], NG=BK/8 granules/row; granule g of row r at
//   slot g^(r&(NG-1)). Staging source col = ((t%NG)^((t/NG)&(NG-1)))*8;
//   frag read slot (c*4+quad)^(l16&(NG-1)).
// BK=64: __launch_bounds__(256,4), 32KB LDS, 4 blocks/CU (qkv/ffn1).
// BK=128: __launch_bounds__(256,2), 64KB LDS — proj/ffn2 (512-block grids
//   cap at 2 blocks/CU anyway; halves barrier drains).
// swz=1: bijective XCD-blocked remap (gridDim.y % 8 == 0 required).
// VtT != nullptr (qkv only): blocks with n0+wn >= 2048 are the V part of
//   the fused QKV output; each wave's 64x64 subtile = one head's
//   (token x hd) tile. Transpose via per-wave LDS (stride 74, two 32-token
//   passes) and write Vt[((b*16+h)*64+hd)*1024 + tok] directly; the qkv
//   buffer itself is NOT written for V blocks (nothing reads it).
template <int BK>
__global__ void __launch_bounds__(256, (BK == 64 ? 4 : 2))
gemm_bt(const ushort_t* __restrict__ A,
        const ushort_t* __restrict__ Bw,
        const float* __restrict__ bias,
        const float* __restrict__ ResF,
        const ushort_t* __restrict__ ResB,
        ushort_t* __restrict__ Cb,
        float* __restrict__ Cf,
        ushort_t* __restrict__ VtT,
        int M, int N, int K, int act, int swz) {
  constexpr int NG = BK / 8;        // granules per row
  constexpr int GM = NG - 1;        // XOR mask
  constexpr int RPP = 2048 / BK;    // rows staged per pass
  constexpr int NP = BK / 16;       // passes per tile
  constexpr int NC = BK / 32;       // k-chunks per K-step
  __shared__ __align__(16) ushort_t sAB[2 * 128 * BK];
  ushort_t* sA = sAB;
  ushort_t* sB = sAB + 128 * BK;
  int t = threadIdx.x;
  int wave = t >> 6, lane = t & 63;
  int quad = lane >> 4, l16 = lane & 15;
  int wm = (wave & 1) * 64, wn = (wave >> 1) * 64;

  int bx = blockIdx.x, by = blockIdx.y;
  if (swz) {
    int lid = by * gridDim.x + bx;
    int xcd = lid & 7, slot = lid >> 3;
    int mchunk = gridDim.y >> 3;           // m-tiles per XCD
    by = xcd * mchunk + slot / gridDim.x;
    bx = slot % gridDim.x;
  }
  int m0 = by * 128, n0 = bx * 128;

  f32x4 zero = {0.f, 0.f, 0.f, 0.f};
  f32x4 acc[4][4];
#pragma unroll
  for (int i = 0; i < 4; i++)
#pragma unroll
    for (int j = 0; j < 4; j++) acc[i][j] = zero;

  int srow = t / NG;
  int scol = ((t & GM) ^ (srow & GM)) * 8;
  const ushort_t* gA = A + (size_t)(m0 + srow) * K + scol;
  const ushort_t* gB = Bw + (size_t)(n0 + srow) * K + scol;

  for (int k0 = 0; k0 < K; k0 += BK) {
#pragma unroll
    for (int p = 0; p < NP; p++) {
      async_ld16(gA + (size_t)p * RPP * K + k0, sA + p * 2048 + wave * 512);
      async_ld16(gB + (size_t)p * RPP * K + k0, sB + p * 2048 + wave * 512);
    }
    __syncthreads();
#pragma unroll
    for (int c = 0; c < NC; c++) {
      int col = (((c * 4 + quad) ^ (l16 & GM)) * 8);
      bf16x8 af[4], bfr[4];
#pragma unroll
      for (int i = 0; i < 4; i++) {
        af[i]  = *(const bf16x8*)(sA + (wm + i * 16 + l16) * BK + col);
        bfr[i] = *(const bf16x8*)(sB + (wn + i * 16 + l16) * BK + col);
      }
#pragma unroll
      for (int mi = 0; mi < 4; mi++)
#pragma unroll
        for (int ni = 0; ni < 4; ni++)
          acc[mi][ni] = __builtin_amdgcn_mfma_f32_16x16x32_bf16(af[mi], bfr[ni], acc[mi][ni], 0, 0, 0);
    }
    __syncthreads();
  }

  // epilogue: C/D layout row = quad*4+r, col = l16 (m89/m91-verified)
  float bv[4];
#pragma unroll
  for (int ni = 0; ni < 4; ni++) bv[ni] = bias[n0 + wn + ni * 16 + l16];

  if (Cf) {
    // f32 output path (ffn2): scalar dword stores, 64B/quad coalesced
#pragma unroll
    for (int mi = 0; mi < 4; mi++) {
      int row = m0 + wm + mi * 16 + quad * 4;
#pragma unroll
      for (int ni = 0; ni < 4; ni++) {
        int col = n0 + wn + ni * 16 + l16;
#pragma unroll
        for (int r = 0; r < 4; r++) {
          size_t idx = (size_t)(row + r) * N + col;
          float vv = acc[mi][ni][r] + bv[ni];
          if (act) vv = gelu_f(vv);
          if (ResB) vv += bf2f(ResB[idx]);
          Cf[idx] = vv;
        }
      }
    }
  } else if (VtT && n0 + wn >= 2048) {
    // fused V-transpose epilogue (qkv V region). Wave's 64x64 subtile =
    // tokens (m0+wm..+63) x head h cols (hd 0..63). Two 32-token passes
    // through per-wave LDS [32][74] (stride 74: bank-spread transpose read),
    // then 16B/lane Vt stores (4 lanes = 64B contiguous per hd row).
    int h = (n0 + wn - 2048) >> 6;
    int bb = m0 >> 10;                    // batch (128-row tile within batch)
    int bh = bb * 16 + h;
    int tok0 = (m0 & 1023) + wm;
    ushort_t* eb2 = sAB + wave * 2368;    // 32*74 per wave, 4x2368 <= 16384
#pragma unroll
    for (int p = 0; p < 2; p++) {
#pragma unroll
      for (int mm = 0; mm < 2; mm++) {
        int mi = 2 * p + mm;
#pragma unroll
        for (int ni = 0; ni < 4; ni++)
#pragma unroll
          for (int r = 0; r < 4; r++)
            eb2[(mm * 16 + quad * 4 + r) * 74 + ni * 16 + l16] =
                f2bf(acc[mi][ni][r] + bv[ni]);
      }
      // same-wave ds write->read, in-order; pass p+1 writes cannot bypass
      // pass p reads (same addresses, WAR preserved per-wave)
#pragma unroll
      for (int it = 0; it < 4; it++) {
        int gid = it * 64 + lane;
        int hd = gid >> 2, tg = gid & 3;
        u16x8 o;
#pragma unroll
        for (int j = 0; j < 8; j++) o[j] = eb2[(tg * 8 + j) * 74 + hd];
        *(u16x8*)(VtT + ((size_t)(bh * 64 + hd)) * 1024 + tok0 + p * 32 + tg * 8) = o;
      }
    }
  } else {
    // bf16 output path: per-wave LDS repack (aliases sA; all K-loop reads
    // completed at final barrier) -> 16B/lane stores
    ushort_t* eb = sAB + wave * (16 * 72);
    int lr = lane >> 2, lc = (lane & 3) * 8;
#pragma unroll
    for (int mi = 0; mi < 4; mi++) {
      int row = m0 + wm + mi * 16;
#pragma unroll
      for (int ni = 0; ni < 4; ni++)
#pragma unroll
        for (int r = 0; r < 4; r++) {
          float vv = acc[mi][ni][r] + bv[ni];
          if (act) vv = gelu_f(vv);
          eb[(quad * 4 + r) * 72 + ni * 16 + l16] = f2bf(vv);
        }
      // same-wave ds write->read (in-order); coalesced u16x8 global stores
#pragma unroll
      for (int hc = 0; hc < 64; hc += 32) {
        u16x8 o = *(const u16x8*)(eb + lr * 72 + hc + lc);
        size_t gidx = (size_t)(row + lr) * N + n0 + wn + hc + lc;
        if (ResF) {
          float4 ra = *(const float4*)(ResF + gidx);
          float4 rb = *(const float4*)(ResF + gidx + 4);
          u16x8 o2;
          o2[0] = f2bf(bf2f(o[0]) + ra.x); o2[1] = f2bf(bf2f(o[1]) + ra.y);
          o2[2] = f2bf(bf2f(o[2]) + ra.z); o2[3] = f2bf(bf2f(o[3]) + ra.w);
          o2[4] = f2bf(bf2f(o[4]) + rb.x); o2[5] = f2bf(bf2f(o[5]) + rb.y);
          o2[6] = f2bf(bf2f(o[6]) + rb.z); o2[7] = f2bf(bf2f(o[7]) + rb.w);
          *(u16x8*)(Cb + gidx) = o2;
        } else {
          *(u16x8*)(Cb + gidx) = o;
        }
      }
    }
  }
}

// ---------------- Flash attention, S^T formulation (R10 version) ------------
__global__ void __launch_bounds__(256) attn_kernel(const ushort_t* __restrict__ qkv,
                                                   const ushort_t* __restrict__ Vt,
                                                   ushort_t* __restrict__ ctx) {
  __shared__ __align__(16) ushort_t sK[128 * 64];
  __shared__ __align__(16) ushort_t sV[64 * 128];
  __shared__ __align__(16) ushort_t sP[4 * 16 * 152];
  int t = threadIdx.x, wave = t >> 6, lane = t & 63;
  int quad = lane >> 4, l16 = lane & 15;
  int bh = blockIdx.y, b = bh >> 4, h = bh & 15;
  int q0 = blockIdx.x * 64 + wave * 16;
  size_t tokbase = (size_t)b * 1024;
  const float SC2 = 0.18033688011112042f;  // 0.125 * log2(e)

  const ushort_t* qrow = qkv + (tokbase + q0 + l16) * 3072 + h * 64;
  bf16x8 qf0 = *(const bf16x8*)(qrow + quad * 8);
  bf16x8 qf1 = *(const bf16x8*)(qrow + 32 + quad * 8);

  f32x4 zero = {0.f, 0.f, 0.f, 0.f};
  f32x4 O[4];
#pragma unroll
  for (int i = 0; i < 4; i++) O[i] = zero;
  float m2 = -3.0e38f, l = 0.f;

  int kvlK = wave * 32 + (lane >> 3);
  int hdKx = lane & 7;
  ushort_t* pw = sP + wave * (16 * 152);

  for (int kv0 = 0; kv0 < 1024; kv0 += 128) {
#pragma unroll
    for (int j = 0; j < 4; j++) {
      int kvl = kvlK + j * 8;
      int hd = (hdKx ^ (kvl & 7)) * 8;
      async_ld16(qkv + (tokbase + kv0 + kvl) * 3072 + 1024 + h * 64 + hd,
                 sK + wave * 2048 + j * 512);
      int hdv = wave * 16 + j * 4 + (lane >> 4);
      int kvloc = ((lane & 15) ^ (hdv & 15)) * 8;
      async_ld16(Vt + ((size_t)bh * 64 + hdv) * 1024 + kv0 + kvloc,
                 sV + wave * 2048 + j * 512);
    }
    __syncthreads();

    f32x4 st[8];
    __builtin_amdgcn_s_setprio(1);
#pragma unroll
    for (int s = 0; s < 8; s++) {
      bf16x8 kf0 = *(const bf16x8*)(sK + (s * 16 + l16) * 64 + ((quad ^ (l16 & 7)) * 8));
      bf16x8 kf1 = *(const bf16x8*)(sK + (s * 16 + l16) * 64 + (((4 + quad) ^ (l16 & 7)) * 8));
      st[s] = __builtin_amdgcn_mfma_f32_16x16x32_bf16(kf0, qf0, zero, 0, 0, 0);
      st[s] = __builtin_amdgcn_mfma_f32_16x16x32_bf16(kf1, qf1, st[s], 0, 0, 0);
    }
    __builtin_amdgcn_s_setprio(0);
    f32x4 mx4 = st[0];
#pragma unroll
    for (int s = 1; s < 8; s++)
#pragma unroll
      for (int r = 0; r < 4; r++) mx4[r] = fmaxf(mx4[r], st[s][r]);
    float mx = fmaxf(fmaxf(mx4[0], mx4[1]), fmaxf(mx4[2], mx4[3]));
    mx = fmaxf(mx, __shfl_xor(mx, 16));
    mx = fmaxf(mx, __shfl_xor(mx, 32));
    float mx2 = mx * SC2;
    if (!__all(mx2 - m2 <= 8.0f)) {
      float mnew2 = fmaxf(m2, mx2);
      float alpha = fast_exp2(m2 - mnew2);
      m2 = mnew2;
      l *= alpha;
#pragma unroll
      for (int ti = 0; ti < 4; ti++)
#pragma unroll
        for (int r = 0; r < 4; r++) O[ti][r] *= alpha;
    }
    float rs = 0.f;
#pragma unroll
    for (int s = 0; s < 8; s++)
#pragma unroll
      for (int r = 0; r < 4; r++) {
        st[s][r] = fast_exp2(fmaf(st[s][r], SC2, -m2));
        rs += st[s][r];
      }
    rs += __shfl_xor(rs, 16);
    rs += __shfl_xor(rs, 32);
    l += rs;
#pragma unroll
    for (int s = 0; s < 8; s++) {
      uint2 pk;
      pk.x = __builtin_amdgcn_perm(__float_as_uint(st[s][1]), __float_as_uint(st[s][0]), 0x07060302u);
      pk.y = __builtin_amdgcn_perm(__float_as_uint(st[s][3]), __float_as_uint(st[s][2]), 0x07060302u);
      *(uint2*)(pw + l16 * 152 + s * 16 + quad * 4) = pk;
    }
    __builtin_amdgcn_s_setprio(1);
#pragma unroll
    for (int c = 0; c < 4; c++) {
      bf16x8 pf = *(const bf16x8*)(pw + l16 * 152 + c * 32 + quad * 8);
#pragma unroll
      for (int ti = 0; ti < 4; ti++) {
        bf16x8 vf = *(const bf16x8*)(sV + (ti * 16 + l16) * 128 + (((c * 4 + quad) ^ l16) * 8));
        O[ti] = __builtin_amdgcn_mfma_f32_16x16x32_bf16(vf, pf, O[ti], 0, 0, 0);
      }
    }
    __builtin_amdgcn_s_setprio(0);
    __syncthreads();
  }
  float inv = 1.0f / l;
  ushort_t* cb = ctx + (tokbase + q0 + l16) * 1024 + h * 64;
#pragma unroll
  for (int ti = 0; ti < 4; ti++) {
    uint2 pk;
    pk.x = (unsigned int)f2bf(O[ti][0] * inv) | ((unsigned int)f2bf(O[ti][1] * inv) << 16);
    pk.y = (unsigned int)f2bf(O[ti][2] * inv) | ((unsigned int)f2bf(O[ti][3] * inv) << 16);
    *(uint2*)(cb + ti * 16 + quad * 4) = pk;
  }
}

extern "C" void kernel_launch(void* const* d_in, const int* in_sizes, int n_in,
                              void* d_out, int out_size, void* d_ws, size_t ws_size,
                              hipStream_t stream) {
  (void)in_sizes; (void)n_in; (void)out_size; (void)ws_size;
  const float* x     = (const float*)d_in[0];
  const float* ln1g  = (const float*)d_in[1];
  const float* ln1b  = (const float*)d_in[2];
  const float* ln2g  = (const float*)d_in[3];
  const float* ln2b  = (const float*)d_in[4];
  const float* Wqkv  = (const float*)d_in[5];
  const float* bqkv  = (const float*)d_in[6];
  const float* Wproj = (const float*)d_in[7];
  const float* bproj = (const float*)d_in[8];
  const float* W1    = (const float*)d_in[9];
  const float* b1    = (const float*)d_in[10];
  const float* W2    = (const float*)d_in[11];
  const float* b2    = (const float*)d_in[12];
  float* out = (float*)d_out;
  char* ws = (char*)d_ws;
  const size_t MB = 1u << 20;
  ushort_t* Wqkv_b  = (ushort_t*)(ws + 0);
  ushort_t* Wproj_b = (ushort_t*)(ws + 6 * MB);
  ushort_t* h1      = (ushort_t*)(ws + 8 * MB);
  ushort_t* qkv     = (ushort_t*)(ws + 24 * MB);
  ushort_t* Vt      = (ushort_t*)(ws + 72 * MB);
  ushort_t* ctx     = (ushort_t*)(ws + 8 * MB);
  ushort_t* out1    = (ushort_t*)(ws + 24 * MB);
  ushort_t* W1_b    = (ushort_t*)(ws + 0);
  ushort_t* h2      = (ushort_t*)(ws + 8 * MB);
  ushort_t* ff1     = (ushort_t*)(ws + 40 * MB);
  ushort_t* W2_b    = (ushort_t*)(ws + 0);

  cvt_f32_bf16_2<<<2048, 256, 0, stream>>>(Wqkv, Wqkv_b, 3 * 1024 * 1024,
                                           Wproj, Wproj_b, 1024 * 1024);
  ln_f32<<<2048, 256, 0, stream>>>(x, ln1g, ln1b, h1);
  gemm_bt<64><<<dim3(24, 64), 256, 0, stream>>>(h1, Wqkv_b, bqkv, nullptr, nullptr, qkv, nullptr, Vt, 8192, 3072, 1024, 0, 0);
  attn_kernel<<<dim3(16, 128), 256, 0, stream>>>(qkv, Vt, ctx);
  gemm_bt<128><<<dim3(8, 64), 256, 0, stream>>>(ctx, Wproj_b, bproj, x, nullptr, out1, nullptr, nullptr, 8192, 1024, 1024, 0, 0);
  cvt_f32_bf16<<<2048, 256, 0, stream>>>(W1, W1_b, 4 * 1024 * 1024);
  ln_bf16<<<2048, 256, 0, stream>>>(out1, ln2g, ln2b, h2);
  gemm_bt<64><<<dim3(32, 64), 256, 0, stream>>>(h2, W1_b, b1, nullptr, nullptr, ff1, nullptr, nullptr, 8192, 4096, 1024, 1, 0);
  cvt_f32_bf16<<<2048, 256, 0, stream>>>(W2, W2_b, 4 * 1024 * 1024);
  gemm_bt<128><<<dim3(8, 64), 256, 0, stream>>>(ff1, W2_b, b2, nullptr, out1, nullptr, out, nullptr, 8192, 1024, 4096, 1, 1);
}

// Round 7
// 479.743 us; speedup vs baseline: 1.2194x; 1.0139x over previous
//
#include <hip/hip_runtime.h>

// Problem: B=8, N=1024, D=1024, H=16, HD=64, FF=4096. Tokens M = 8192.
// Inputs f32, OUTPUT f32. Internals bf16, f32 accumulation.
// Round 14: template-split the V-fusion. R6 showed the added VtT epilogue
// branch (runtime) bloated the SHARED gemm template 64->88 VGPR and cost
// ffn2 ~14us (98 vs <=84 in R3) despite being dead code there. VF is now a
// template param: VF=0 (proj/ffn1/ffn2) folds the branch -> 64-VGPR codegen;
// only qkv (<64,1>) carries the V-transpose epilogue. No other changes.

typedef unsigned short ushort_t;
typedef __bf16 bf16x8 __attribute__((ext_vector_type(8)));
typedef float f32x4 __attribute__((ext_vector_type(4)));
typedef unsigned short u16x8 __attribute__((ext_vector_type(8)));

__device__ __forceinline__ void async_ld16(const void* g, void* l) {
  // global -> LDS direct, 16B per lane. LDS dst is wave-uniform base; HW
  // writes base + lane*16.
  __builtin_amdgcn_global_load_lds(
      (void __attribute__((address_space(1)))*)const_cast<void*>(g),
      (void __attribute__((address_space(3)))*)l, 16, 0, 0);
}

__device__ __forceinline__ float bf2f(ushort_t h) {
  union { unsigned int u; float f; } v;
  v.u = ((unsigned int)h) << 16;
  return v.f;
}
__device__ __forceinline__ ushort_t f2bf(float f) {
  union { float f; unsigned int u; } v;
  v.f = f;
  unsigned int r = v.u + 0x7FFFu + ((v.u >> 16) & 1u);  // RNE
  return (ushort_t)(r >> 16);
}
// 2^x via HW v_exp_f32 (D = 2^S0 per ISA); guarded fallback keeps semantics.
__device__ __forceinline__ float fast_exp2(float x) {
#if __has_builtin(__builtin_amdgcn_exp2f)
  return __builtin_amdgcn_exp2f(x);
#else
  return __expf(x * 0.6931471805599453f);
#endif
}
// tanh-form GELU (~3e-4 dev from exact erf; 0.078 threshold headroom)
__device__ __forceinline__ float gelu_f(float x) {
  float y = 0.7978845608028654f * (x + 0.044715f * x * x * x);
  float e = __expf(2.0f * y);
  float t = 1.0f - 2.0f / (e + 1.0f);
  return 0.5f * x * (1.0f + t);
}

// ---------------- f32 -> bf16 weight conversion (8 elems/thread) ------------
__global__ void __launch_bounds__(256) cvt_f32_bf16(const float* __restrict__ src,
                                                    ushort_t* __restrict__ dst, int n) {
  int i = (blockIdx.x * 256 + threadIdx.x) * 8;
  if (i >= n) return;
  float4 a = *(const float4*)(src + i);
  float4 b = *(const float4*)(src + i + 4);
  u16x8 o;
  o[0] = f2bf(a.x); o[1] = f2bf(a.y); o[2] = f2bf(a.z); o[3] = f2bf(a.w);
  o[4] = f2bf(b.x); o[5] = f2bf(b.y); o[6] = f2bf(b.z); o[7] = f2bf(b.w);
  *(u16x8*)(dst + i) = o;
}

// two-buffer variant: one launch for Wqkv (n0) + Wproj (n1), non-aliasing dsts
__global__ void __launch_bounds__(256) cvt_f32_bf16_2(const float* __restrict__ s0,
                                                      ushort_t* __restrict__ d0, int n0,
                                                      const float* __restrict__ s1,
                                                      ushort_t* __restrict__ d1, int n1) {
  int i = (blockIdx.x * 256 + threadIdx.x) * 8;
  const float* src;
  ushort_t* dst;
  if (i < n0) {
    src = s0 + i; dst = d0 + i;
  } else {
    int j = i - n0;
    if (j >= n1) return;
    src = s1 + j; dst = d1 + j;
  }
  float4 a = *(const float4*)(src);
  float4 b = *(const float4*)(src + 4);
  u16x8 o;
  o[0] = f2bf(a.x); o[1] = f2bf(a.y); o[2] = f2bf(a.z); o[3] = f2bf(a.w);
  o[4] = f2bf(b.x); o[5] = f2bf(b.y); o[6] = f2bf(b.z); o[7] = f2bf(b.w);
  *(u16x8*)dst = o;
}

// ---------------- LayerNorm (f32 in, bf16 out): 1 wave per token ------------
__global__ void __launch_bounds__(256) ln_f32(const float* __restrict__ X,
                                              const float* __restrict__ G,
                                              const float* __restrict__ Bb,
                                              ushort_t* __restrict__ Y) {
  int tok = blockIdx.x * 4 + (threadIdx.x >> 6);
  int lane = threadIdx.x & 63;
  const float* xr = X + (size_t)tok * 1024 + lane * 16;
  float v[16];
#pragma unroll
  for (int c = 0; c < 4; c++) {
    float4 a = *(const float4*)(xr + c * 4);
    v[c * 4 + 0] = a.x; v[c * 4 + 1] = a.y; v[c * 4 + 2] = a.z; v[c * 4 + 3] = a.w;
  }
  float s = 0.f, ss = 0.f;
#pragma unroll
  for (int j = 0; j < 16; j++) { s += v[j]; ss += v[j] * v[j]; }
#pragma unroll
  for (int off = 32; off >= 1; off >>= 1) {
    s += __shfl_xor(s, off);
    ss += __shfl_xor(ss, off);
  }
  float mu = s * (1.f / 1024.f);
  float var = ss * (1.f / 1024.f) - mu * mu;
  float rs = rsqrtf(var + 1e-5f);
  u16x8 o0, o1;
#pragma unroll
  for (int c = 0; c < 4; c++) {
    float4 g = *(const float4*)(G + lane * 16 + c * 4);
    float4 bb = *(const float4*)(Bb + lane * 16 + c * 4);
    ushort_t* op = (c < 2) ? (ushort_t*)&o0 : (ushort_t*)&o1;
    int base = (c & 1) * 4;
    op[base + 0] = f2bf((v[c * 4 + 0] - mu) * rs * g.x + bb.x);
    op[base + 1] = f2bf((v[c * 4 + 1] - mu) * rs * g.y + bb.y);
    op[base + 2] = f2bf((v[c * 4 + 2] - mu) * rs * g.z + bb.z);
    op[base + 3] = f2bf((v[c * 4 + 3] - mu) * rs * g.w + bb.w);
  }
  ushort_t* yr = Y + (size_t)tok * 1024 + lane * 16;
  *(u16x8*)yr = o0;
  *(u16x8*)(yr + 8) = o1;
}

// ---------------- LayerNorm (bf16 in, bf16 out): 1 wave per token -----------
__global__ void __launch_bounds__(256) ln_bf16(const ushort_t* __restrict__ X,
                                               const float* __restrict__ G,
                                               const float* __restrict__ Bb,
                                               ushort_t* __restrict__ Y) {
  int tok = blockIdx.x * 4 + (threadIdx.x >> 6);
  int lane = threadIdx.x & 63;
  const ushort_t* xr = X + (size_t)tok * 1024 + lane * 16;
  u16x8 x0 = *(const u16x8*)xr;
  u16x8 x1 = *(const u16x8*)(xr + 8);
  float v[16];
  float s = 0.f, ss = 0.f;
#pragma unroll
  for (int j = 0; j < 8; j++) { v[j] = bf2f(x0[j]); v[8 + j] = bf2f(x1[j]); }
#pragma unroll
  for (int j = 0; j < 16; j++) { s += v[j]; ss += v[j] * v[j]; }
#pragma unroll
  for (int off = 32; off >= 1; off >>= 1) {
    s += __shfl_xor(s, off);
    ss += __shfl_xor(ss, off);
  }
  float mu = s * (1.f / 1024.f);
  float var = ss * (1.f / 1024.f) - mu * mu;
  float rs = rsqrtf(var + 1e-5f);
  u16x8 o0, o1;
#pragma unroll
  for (int c = 0; c < 4; c++) {
    float4 g = *(const float4*)(G + lane * 16 + c * 4);
    float4 bb = *(const float4*)(Bb + lane * 16 + c * 4);
    ushort_t* op = (c < 2) ? (ushort_t*)&o0 : (ushort_t*)&o1;
    int base = (c & 1) * 4;
    op[base + 0] = f2bf((v[c * 4 + 0] - mu) * rs * g.x + bb.x);
    op[base + 1] = f2bf((v[c * 4 + 1] - mu) * rs * g.y + bb.y);
    op[base + 2] = f2bf((v[c * 4 + 2] - mu) * rs * g.z + bb.z);
    op[base + 3] = f2bf((v[c * 4 + 3] - mu) * rs * g.w + bb.w);
  }
  ushort_t* yr = Y + (size_t)tok * 1024 + lane * 16;
  *(u16x8*)yr = o0;
  *(u16x8*)(yr + 8) = o1;
}

// ---------------- GEMM: C[M,N] = act(A[M,K] @ B[N,K]^T + bias) (+Res) -------
// 128x128 tile, template BK in {64,128}, 4 waves 2x2, 4x4 frags of 16x16x32
// bf16 MFMA, global_load_lds width=16 staging, K/BK K-iters.
// Tiles: row-major [128][BK], NG=BK/8 granules/row; granule g of row r at
//   slot g^(r&(NG-1)). Staging source col = ((t%NG)^((t/NG)&(NG-1)))*8;
//   frag read slot (c*4+quad)^(l16&(NG-1)).
// BK=64: __launch_bounds__(256,4), 32KB LDS, 4 blocks/CU (qkv/ffn1).
// BK=128: __launch_bounds__(256,2), 64KB LDS — proj/ffn2 (512-block grids
//   cap at 2 blocks/CU anyway; halves barrier drains).
// swz=1: bijective XCD-blocked remap (gridDim.y % 8 == 0 required).
// VF=1 (qkv only; compile-time so VF=0 keeps the proven 64-VGPR codegen):
//   blocks with n0+wn >= 2048 are the V part of fused QKV; each wave's
//   64x64 subtile = one head's (token x hd) tile. Transpose via per-wave
//   LDS (stride 74) and write Vt[b,h,hd,tok] directly; qkv buffer not
//   written for V blocks (nothing reads it).
template <int BK, int VF>
__global__ void __launch_bounds__(256, (BK == 64 ? 4 : 2))
gemm_bt(const ushort_t* __restrict__ A,
        const ushort_t* __restrict__ Bw,
        const float* __restrict__ bias,
        const float* __restrict__ ResF,
        const ushort_t* __restrict__ ResB,
        ushort_t* __restrict__ Cb,
        float* __restrict__ Cf,
        ushort_t* __restrict__ VtT,
        int M, int N, int K, int act, int swz) {
  constexpr int NG = BK / 8;        // granules per row
  constexpr int GM = NG - 1;        // XOR mask
  constexpr int RPP = 2048 / BK;    // rows staged per pass
  constexpr int NP = BK / 16;       // passes per tile
  constexpr int NC = BK / 32;       // k-chunks per K-step
  __shared__ __align__(16) ushort_t sAB[2 * 128 * BK];
  ushort_t* sA = sAB;
  ushort_t* sB = sAB + 128 * BK;
  int t = threadIdx.x;
  int wave = t >> 6, lane = t & 63;
  int quad = lane >> 4, l16 = lane & 15;
  int wm = (wave & 1) * 64, wn = (wave >> 1) * 64;

  int bx = blockIdx.x, by = blockIdx.y;
  if (swz) {
    int lid = by * gridDim.x + bx;
    int xcd = lid & 7, slot = lid >> 3;
    int mchunk = gridDim.y >> 3;           // m-tiles per XCD
    by = xcd * mchunk + slot / gridDim.x;
    bx = slot % gridDim.x;
  }
  int m0 = by * 128, n0 = bx * 128;

  f32x4 zero = {0.f, 0.f, 0.f, 0.f};
  f32x4 acc[4][4];
#pragma unroll
  for (int i = 0; i < 4; i++)
#pragma unroll
    for (int j = 0; j < 4; j++) acc[i][j] = zero;

  int srow = t / NG;
  int scol = ((t & GM) ^ (srow & GM)) * 8;
  const ushort_t* gA = A + (size_t)(m0 + srow) * K + scol;
  const ushort_t* gB = Bw + (size_t)(n0 + srow) * K + scol;

  for (int k0 = 0; k0 < K; k0 += BK) {
#pragma unroll
    for (int p = 0; p < NP; p++) {
      async_ld16(gA + (size_t)p * RPP * K + k0, sA + p * 2048 + wave * 512);
      async_ld16(gB + (size_t)p * RPP * K + k0, sB + p * 2048 + wave * 512);
    }
    __syncthreads();
#pragma unroll
    for (int c = 0; c < NC; c++) {
      int col = (((c * 4 + quad) ^ (l16 & GM)) * 8);
      bf16x8 af[4], bfr[4];
#pragma unroll
      for (int i = 0; i < 4; i++) {
        af[i]  = *(const bf16x8*)(sA + (wm + i * 16 + l16) * BK + col);
        bfr[i] = *(const bf16x8*)(sB + (wn + i * 16 + l16) * BK + col);
      }
#pragma unroll
      for (int mi = 0; mi < 4; mi++)
#pragma unroll
        for (int ni = 0; ni < 4; ni++)
          acc[mi][ni] = __builtin_amdgcn_mfma_f32_16x16x32_bf16(af[mi], bfr[ni], acc[mi][ni], 0, 0, 0);
    }
    __syncthreads();
  }

  // epilogue: C/D layout row = quad*4+r, col = l16 (m89/m91-verified)
  float bv[4];
#pragma unroll
  for (int ni = 0; ni < 4; ni++) bv[ni] = bias[n0 + wn + ni * 16 + l16];

  if (Cf) {
    // f32 output path (ffn2): scalar dword stores, 64B/quad coalesced
#pragma unroll
    for (int mi = 0; mi < 4; mi++) {
      int row = m0 + wm + mi * 16 + quad * 4;
#pragma unroll
      for (int ni = 0; ni < 4; ni++) {
        int col = n0 + wn + ni * 16 + l16;
#pragma unroll
        for (int r = 0; r < 4; r++) {
          size_t idx = (size_t)(row + r) * N + col;
          float vv = acc[mi][ni][r] + bv[ni];
          if (act) vv = gelu_f(vv);
          if (ResB) vv += bf2f(ResB[idx]);
          Cf[idx] = vv;
        }
      }
    }
  } else if (VF && n0 + wn >= 2048) {
    // fused V-transpose epilogue (qkv V region, VF=1 instantiation only).
    int h = (n0 + wn - 2048) >> 6;
    int bb = m0 >> 10;                    // batch
    int bh = bb * 16 + h;
    int tok0 = (m0 & 1023) + wm;
    ushort_t* eb2 = sAB + wave * 2368;    // 32*74 per wave, 4x2368 <= 16384
#pragma unroll
    for (int p = 0; p < 2; p++) {
#pragma unroll
      for (int mm = 0; mm < 2; mm++) {
        int mi = 2 * p + mm;
#pragma unroll
        for (int ni = 0; ni < 4; ni++)
#pragma unroll
          for (int r = 0; r < 4; r++)
            eb2[(mm * 16 + quad * 4 + r) * 74 + ni * 16 + l16] =
                f2bf(acc[mi][ni][r] + bv[ni]);
      }
      // same-wave ds write->read, in-order; WAR preserved per-wave
#pragma unroll
      for (int it = 0; it < 4; it++) {
        int gid = it * 64 + lane;
        int hd = gid >> 2, tg = gid & 3;
        u16x8 o;
#pragma unroll
        for (int j = 0; j < 8; j++) o[j] = eb2[(tg * 8 + j) * 74 + hd];
        *(u16x8*)(VtT + ((size_t)(bh * 64 + hd)) * 1024 + tok0 + p * 32 + tg * 8) = o;
      }
    }
  } else {
    // bf16 output path: per-wave LDS repack (aliases sA; all K-loop reads
    // completed at final barrier) -> 16B/lane stores
    ushort_t* eb = sAB + wave * (16 * 72);
    int lr = lane >> 2, lc = (lane & 3) * 8;
#pragma unroll
    for (int mi = 0; mi < 4; mi++) {
      int row = m0 + wm + mi * 16;
#pragma unroll
      for (int ni = 0; ni < 4; ni++)
#pragma unroll
        for (int r = 0; r < 4; r++) {
          float vv = acc[mi][ni][r] + bv[ni];
          if (act) vv = gelu_f(vv);
          eb[(quad * 4 + r) * 72 + ni * 16 + l16] = f2bf(vv);
        }
      // same-wave ds write->read (in-order); coalesced u16x8 global stores
#pragma unroll
      for (int hc = 0; hc < 64; hc += 32) {
        u16x8 o = *(const u16x8*)(eb + lr * 72 + hc + lc);
        size_t gidx = (size_t)(row + lr) * N + n0 + wn + hc + lc;
        if (ResF) {
          float4 ra = *(const float4*)(ResF + gidx);
          float4 rb = *(const float4*)(ResF + gidx + 4);
          u16x8 o2;
          o2[0] = f2bf(bf2f(o[0]) + ra.x); o2[1] = f2bf(bf2f(o[1]) + ra.y);
          o2[2] = f2bf(bf2f(o[2]) + ra.z); o2[3] = f2bf(bf2f(o[3]) + ra.w);
          o2[4] = f2bf(bf2f(o[4]) + rb.x); o2[5] = f2bf(bf2f(o[5]) + rb.y);
          o2[6] = f2bf(bf2f(o[6]) + rb.z); o2[7] = f2bf(bf2f(o[7]) + rb.w);
          *(u16x8*)(Cb + gidx) = o2;
        } else {
          *(u16x8*)(Cb + gidx) = o;
        }
      }
    }
  }
}

// ---------------- Flash attention, S^T formulation (R10 version) ------------
__global__ void __launch_bounds__(256) attn_kernel(const ushort_t* __restrict__ qkv,
                                                   const ushort_t* __restrict__ Vt,
                                                   ushort_t* __restrict__ ctx) {
  __shared__ __align__(16) ushort_t sK[128 * 64];
  __shared__ __align__(16) ushort_t sV[64 * 128];
  __shared__ __align__(16) ushort_t sP[4 * 16 * 152];
  int t = threadIdx.x, wave = t >> 6, lane = t & 63;
  int quad = lane >> 4, l16 = lane & 15;
  int bh = blockIdx.y, b = bh >> 4, h = bh & 15;
  int q0 = blockIdx.x * 64 + wave * 16;
  size_t tokbase = (size_t)b * 1024;
  const float SC2 = 0.18033688011112042f;  // 0.125 * log2(e)

  const ushort_t* qrow = qkv + (tokbase + q0 + l16) * 3072 + h * 64;
  bf16x8 qf0 = *(const bf16x8*)(qrow + quad * 8);
  bf16x8 qf1 = *(const bf16x8*)(qrow + 32 + quad * 8);

  f32x4 zero = {0.f, 0.f, 0.f, 0.f};
  f32x4 O[4];
#pragma unroll
  for (int i = 0; i < 4; i++) O[i] = zero;
  float m2 = -3.0e38f, l = 0.f;

  int kvlK = wave * 32 + (lane >> 3);
  int hdKx = lane & 7;
  ushort_t* pw = sP + wave * (16 * 152);

  for (int kv0 = 0; kv0 < 1024; kv0 += 128) {
#pragma unroll
    for (int j = 0; j < 4; j++) {
      int kvl = kvlK + j * 8;
      int hd = (hdKx ^ (kvl & 7)) * 8;
      async_ld16(qkv + (tokbase + kv0 + kvl) * 3072 + 1024 + h * 64 + hd,
                 sK + wave * 2048 + j * 512);
      int hdv = wave * 16 + j * 4 + (lane >> 4);
      int kvloc = ((lane & 15) ^ (hdv & 15)) * 8;
      async_ld16(Vt + ((size_t)bh * 64 + hdv) * 1024 + kv0 + kvloc,
                 sV + wave * 2048 + j * 512);
    }
    __syncthreads();

    f32x4 st[8];
    __builtin_amdgcn_s_setprio(1);
#pragma unroll
    for (int s = 0; s < 8; s++) {
      bf16x8 kf0 = *(const bf16x8*)(sK + (s * 16 + l16) * 64 + ((quad ^ (l16 & 7)) * 8));
      bf16x8 kf1 = *(const bf16x8*)(sK + (s * 16 + l16) * 64 + (((4 + quad) ^ (l16 & 7)) * 8));
      st[s] = __builtin_amdgcn_mfma_f32_16x16x32_bf16(kf0, qf0, zero, 0, 0, 0);
      st[s] = __builtin_amdgcn_mfma_f32_16x16x32_bf16(kf1, qf1, st[s], 0, 0, 0);
    }
    __builtin_amdgcn_s_setprio(0);
    f32x4 mx4 = st[0];
#pragma unroll
    for (int s = 1; s < 8; s++)
#pragma unroll
      for (int r = 0; r < 4; r++) mx4[r] = fmaxf(mx4[r], st[s][r]);
    float mx = fmaxf(fmaxf(mx4[0], mx4[1]), fmaxf(mx4[2], mx4[3]));
    mx = fmaxf(mx, __shfl_xor(mx, 16));
    mx = fmaxf(mx, __shfl_xor(mx, 32));
    float mx2 = mx * SC2;
    if (!__all(mx2 - m2 <= 8.0f)) {
      float mnew2 = fmaxf(m2, mx2);
      float alpha = fast_exp2(m2 - mnew2);
      m2 = mnew2;
      l *= alpha;
#pragma unroll
      for (int ti = 0; ti < 4; ti++)
#pragma unroll
        for (int r = 0; r < 4; r++) O[ti][r] *= alpha;
    }
    float rs = 0.f;
#pragma unroll
    for (int s = 0; s < 8; s++)
#pragma unroll
      for (int r = 0; r < 4; r++) {
        st[s][r] = fast_exp2(fmaf(st[s][r], SC2, -m2));
        rs += st[s][r];
      }
    rs += __shfl_xor(rs, 16);
    rs += __shfl_xor(rs, 32);
    l += rs;
#pragma unroll
    for (int s = 0; s < 8; s++) {
      uint2 pk;
      pk.x = __builtin_amdgcn_perm(__float_as_uint(st[s][1]), __float_as_uint(st[s][0]), 0x07060302u);
      pk.y = __builtin_amdgcn_perm(__float_as_uint(st[s][3]), __float_as_uint(st[s][2]), 0x07060302u);
      *(uint2*)(pw + l16 * 152 + s * 16 + quad * 4) = pk;
    }
    __builtin_amdgcn_s_setprio(1);
#pragma unroll
    for (int c = 0; c < 4; c++) {
      bf16x8 pf = *(const bf16x8*)(pw + l16 * 152 + c * 32 + quad * 8);
#pragma unroll
      for (int ti = 0; ti < 4; ti++) {
        bf16x8 vf = *(const bf16x8*)(sV + (ti * 16 + l16) * 128 + (((c * 4 + quad) ^ l16) * 8));
        O[ti] = __builtin_amdgcn_mfma_f32_16x16x32_bf16(vf, pf, O[ti], 0, 0, 0);
      }
    }
    __builtin_amdgcn_s_setprio(0);
    __syncthreads();
  }
  float inv = 1.0f / l;
  ushort_t* cb = ctx + (tokbase + q0 + l16) * 1024 + h * 64;
#pragma unroll
  for (int ti = 0; ti < 4; ti++) {
    uint2 pk;
    pk.x = (unsigned int)f2bf(O[ti][0] * inv) | ((unsigned int)f2bf(O[ti][1] * inv) << 16);
    pk.y = (unsigned int)f2bf(O[ti][2] * inv) | ((unsigned int)f2bf(O[ti][3] * inv) << 16);
    *(uint2*)(cb + ti * 16 + quad * 4) = pk;
  }
}

extern "C" void kernel_launch(void* const* d_in, const int* in_sizes, int n_in,
                              void* d_out, int out_size, void* d_ws, size_t ws_size,
                              hipStream_t stream) {
  (void)in_sizes; (void)n_in; (void)out_size; (void)ws_size;
  const float* x     = (const float*)d_in[0];
  const float* ln1g  = (const float*)d_in[1];
  const float* ln1b  = (const float*)d_in[2];
  const float* ln2g  = (const float*)d_in[3];
  const float* ln2b  = (const float*)d_in[4];
  const float* Wqkv  = (const float*)d_in[5];
  const float* bqkv  = (const float*)d_in[6];
  const float* Wproj = (const float*)d_in[7];
  const float* bproj = (const float*)d_in[8];
  const float* W1    = (const float*)d_in[9];
  const float* b1    = (const float*)d_in[10];
  const float* W2    = (const float*)d_in[11];
  const float* b2    = (const float*)d_in[12];
  float* out = (float*)d_out;
  char* ws = (char*)d_ws;
  const size_t MB = 1u << 20;
  ushort_t* Wqkv_b  = (ushort_t*)(ws + 0);
  ushort_t* Wproj_b = (ushort_t*)(ws + 6 * MB);
  ushort_t* h1      = (ushort_t*)(ws + 8 * MB);
  ushort_t* qkv     = (ushort_t*)(ws + 24 * MB);
  ushort_t* Vt      = (ushort_t*)(ws + 72 * MB);
  ushort_t* ctx     = (ushort_t*)(ws + 8 * MB);
  ushort_t* out1    = (ushort_t*)(ws + 24 * MB);
  ushort_t* W1_b    = (ushort_t*)(ws + 0);
  ushort_t* h2      = (ushort_t*)(ws + 8 * MB);
  ushort_t* ff1     = (ushort_t*)(ws + 40 * MB);
  ushort_t* W2_b    = (ushort_t*)(ws + 0);

  cvt_f32_bf16_2<<<2048, 256, 0, stream>>>(Wqkv, Wqkv_b, 3 * 1024 * 1024,
                                           Wproj, Wproj_b, 1024 * 1024);
  ln_f32<<<2048, 256, 0, stream>>>(x, ln1g, ln1b, h1);
  gemm_bt<64, 1><<<dim3(24, 64), 256, 0, stream>>>(h1, Wqkv_b, bqkv, nullptr, nullptr, qkv, nullptr, Vt, 8192, 3072, 1024, 0, 0);
  attn_kernel<<<dim3(16, 128), 256, 0, stream>>>(qkv, Vt, ctx);
  gemm_bt<128, 0><<<dim3(8, 64), 256, 0, stream>>>(ctx, Wproj_b, bproj, x, nullptr, out1, nullptr, nullptr, 8192, 1024, 1024, 0, 0);
  cvt_f32_bf16<<<2048, 256, 0, stream>>>(W1, W1_b, 4 * 1024 * 1024);
  ln_bf16<<<2048, 256, 0, stream>>>(out1, ln2g, ln2b, h2);
  gemm_bt<64, 0><<<dim3(32, 64), 256, 0, stream>>>(h2, W1_b, b1, nullptr, nullptr, ff1, nullptr, nullptr, 8192, 4096, 1024, 1, 0);
  cvt_f32_bf16<<<2048, 256, 0, stream>>>(W2, W2_b, 4 * 1024 * 1024);
  gemm_bt<128, 0><<<dim3(8, 64), 256, 0, stream>>>(ff1, W2_b, b2, nullptr, out1, nullptr, out, nullptr, 8192, 1024, 4096, 1, 1);
}

// Round 8
// 475.570 us; speedup vs baseline: 1.2301x; 1.0088x over previous
//
#include <hip/hip_runtime.h>

// Problem: B=8, N=1024, D=1024, H=16, HD=64, FF=4096. Tokens M = 8192.
// Inputs f32, OUTPUT f32. Internals bf16, f32 accumulation.
// Round 15: attention occupancy push. sP shrunk 19.4KB -> 5KB by kv-quarter
// reuse (per PV slice c: write 2 packed uint2 (s=2c,2c+1) into a per-wave
// 16x40-ushort buffer, b128-read the fragment, 4 MFMA; same-wave in-order
// LDS covers write->read and quarter WAR). Stride 40 ushorts = 80B keeps
// 16B-aligned b128 reads + 2-way (free) banking. LDS 51.2 -> 37.9KB =
// 4 blocks/CU (was 3) on a latency-bound kernel (MfmaUtil 16%).
// GEMMs frozen at R14 config (all at the ~820TF structural ceiling).

typedef unsigned short ushort_t;
typedef __bf16 bf16x8 __attribute__((ext_vector_type(8)));
typedef float f32x4 __attribute__((ext_vector_type(4)));
typedef unsigned short u16x8 __attribute__((ext_vector_type(8)));

__device__ __forceinline__ void async_ld16(const void* g, void* l) {
  // global -> LDS direct, 16B per lane. LDS dst is wave-uniform base; HW
  // writes base + lane*16.
  __builtin_amdgcn_global_load_lds(
      (void __attribute__((address_space(1)))*)const_cast<void*>(g),
      (void __attribute__((address_space(3)))*)l, 16, 0, 0);
}

__device__ __forceinline__ float bf2f(ushort_t h) {
  union { unsigned int u; float f; } v;
  v.u = ((unsigned int)h) << 16;
  return v.f;
}
__device__ __forceinline__ ushort_t f2bf(float f) {
  union { float f; unsigned int u; } v;
  v.f = f;
  unsigned int r = v.u + 0x7FFFu + ((v.u >> 16) & 1u);  // RNE
  return (ushort_t)(r >> 16);
}
// 2^x via HW v_exp_f32 (D = 2^S0 per ISA); guarded fallback keeps semantics.
__device__ __forceinline__ float fast_exp2(float x) {
#if __has_builtin(__builtin_amdgcn_exp2f)
  return __builtin_amdgcn_exp2f(x);
#else
  return __expf(x * 0.6931471805599453f);
#endif
}
// tanh-form GELU (~3e-4 dev from exact erf; 0.078 threshold headroom)
__device__ __forceinline__ float gelu_f(float x) {
  float y = 0.7978845608028654f * (x + 0.044715f * x * x * x);
  float e = __expf(2.0f * y);
  float t = 1.0f - 2.0f / (e + 1.0f);
  return 0.5f * x * (1.0f + t);
}

// ---------------- f32 -> bf16 weight conversion (8 elems/thread) ------------
__global__ void __launch_bounds__(256) cvt_f32_bf16(const float* __restrict__ src,
                                                    ushort_t* __restrict__ dst, int n) {
  int i = (blockIdx.x * 256 + threadIdx.x) * 8;
  if (i >= n) return;
  float4 a = *(const float4*)(src + i);
  float4 b = *(const float4*)(src + i + 4);
  u16x8 o;
  o[0] = f2bf(a.x); o[1] = f2bf(a.y); o[2] = f2bf(a.z); o[3] = f2bf(a.w);
  o[4] = f2bf(b.x); o[5] = f2bf(b.y); o[6] = f2bf(b.z); o[7] = f2bf(b.w);
  *(u16x8*)(dst + i) = o;
}

// two-buffer variant: one launch for Wqkv (n0) + Wproj (n1), non-aliasing dsts
__global__ void __launch_bounds__(256) cvt_f32_bf16_2(const float* __restrict__ s0,
                                                      ushort_t* __restrict__ d0, int n0,
                                                      const float* __restrict__ s1,
                                                      ushort_t* __restrict__ d1, int n1) {
  int i = (blockIdx.x * 256 + threadIdx.x) * 8;
  const float* src;
  ushort_t* dst;
  if (i < n0) {
    src = s0 + i; dst = d0 + i;
  } else {
    int j = i - n0;
    if (j >= n1) return;
    src = s1 + j; dst = d1 + j;
  }
  float4 a = *(const float4*)(src);
  float4 b = *(const float4*)(src + 4);
  u16x8 o;
  o[0] = f2bf(a.x); o[1] = f2bf(a.y); o[2] = f2bf(a.z); o[3] = f2bf(a.w);
  o[4] = f2bf(b.x); o[5] = f2bf(b.y); o[6] = f2bf(b.z); o[7] = f2bf(b.w);
  *(u16x8*)dst = o;
}

// ---------------- LayerNorm (f32 in, bf16 out): 1 wave per token ------------
__global__ void __launch_bounds__(256) ln_f32(const float* __restrict__ X,
                                              const float* __restrict__ G,
                                              const float* __restrict__ Bb,
                                              ushort_t* __restrict__ Y) {
  int tok = blockIdx.x * 4 + (threadIdx.x >> 6);
  int lane = threadIdx.x & 63;
  const float* xr = X + (size_t)tok * 1024 + lane * 16;
  float v[16];
#pragma unroll
  for (int c = 0; c < 4; c++) {
    float4 a = *(const float4*)(xr + c * 4);
    v[c * 4 + 0] = a.x; v[c * 4 + 1] = a.y; v[c * 4 + 2] = a.z; v[c * 4 + 3] = a.w;
  }
  float s = 0.f, ss = 0.f;
#pragma unroll
  for (int j = 0; j < 16; j++) { s += v[j]; ss += v[j] * v[j]; }
#pragma unroll
  for (int off = 32; off >= 1; off >>= 1) {
    s += __shfl_xor(s, off);
    ss += __shfl_xor(ss, off);
  }
  float mu = s * (1.f / 1024.f);
  float var = ss * (1.f / 1024.f) - mu * mu;
  float rs = rsqrtf(var + 1e-5f);
  u16x8 o0, o1;
#pragma unroll
  for (int c = 0; c < 4; c++) {
    float4 g = *(const float4*)(G + lane * 16 + c * 4);
    float4 bb = *(const float4*)(Bb + lane * 16 + c * 4);
    ushort_t* op = (c < 2) ? (ushort_t*)&o0 : (ushort_t*)&o1;
    int base = (c & 1) * 4;
    op[base + 0] = f2bf((v[c * 4 + 0] - mu) * rs * g.x + bb.x);
    op[base + 1] = f2bf((v[c * 4 + 1] - mu) * rs * g.y + bb.y);
    op[base + 2] = f2bf((v[c * 4 + 2] - mu) * rs * g.z + bb.z);
    op[base + 3] = f2bf((v[c * 4 + 3] - mu) * rs * g.w + bb.w);
  }
  ushort_t* yr = Y + (size_t)tok * 1024 + lane * 16;
  *(u16x8*)yr = o0;
  *(u16x8*)(yr + 8) = o1;
}

// ---------------- LayerNorm (bf16 in, bf16 out): 1 wave per token -----------
__global__ void __launch_bounds__(256) ln_bf16(const ushort_t* __restrict__ X,
                                               const float* __restrict__ G,
                                               const float* __restrict__ Bb,
                                               ushort_t* __restrict__ Y) {
  int tok = blockIdx.x * 4 + (threadIdx.x >> 6);
  int lane = threadIdx.x & 63;
  const ushort_t* xr = X + (size_t)tok * 1024 + lane * 16;
  u16x8 x0 = *(const u16x8*)xr;
  u16x8 x1 = *(const u16x8*)(xr + 8);
  float v[16];
  float s = 0.f, ss = 0.f;
#pragma unroll
  for (int j = 0; j < 8; j++) { v[j] = bf2f(x0[j]); v[8 + j] = bf2f(x1[j]); }
#pragma unroll
  for (int j = 0; j < 16; j++) { s += v[j]; ss += v[j] * v[j]; }
#pragma unroll
  for (int off = 32; off >= 1; off >>= 1) {
    s += __shfl_xor(s, off);
    ss += __shfl_xor(ss, off);
  }
  float mu = s * (1.f / 1024.f);
  float var = ss * (1.f / 1024.f) - mu * mu;
  float rs = rsqrtf(var + 1e-5f);
  u16x8 o0, o1;
#pragma unroll
  for (int c = 0; c < 4; c++) {
    float4 g = *(const float4*)(G + lane * 16 + c * 4);
    float4 bb = *(const float4*)(Bb + lane * 16 + c * 4);
    ushort_t* op = (c < 2) ? (ushort_t*)&o0 : (ushort_t*)&o1;
    int base = (c & 1) * 4;
    op[base + 0] = f2bf((v[c * 4 + 0] - mu) * rs * g.x + bb.x);
    op[base + 1] = f2bf((v[c * 4 + 1] - mu) * rs * g.y + bb.y);
    op[base + 2] = f2bf((v[c * 4 + 2] - mu) * rs * g.z + bb.z);
    op[base + 3] = f2bf((v[c * 4 + 3] - mu) * rs * g.w + bb.w);
  }
  ushort_t* yr = Y + (size_t)tok * 1024 + lane * 16;
  *(u16x8*)yr = o0;
  *(u16x8*)(yr + 8) = o1;
}

// ---------------- GEMM: C[M,N] = act(A[M,K] @ B[N,K]^T + bias) (+Res) -------
// 128x128 tile, template BK in {64,128}, 4 waves 2x2, 4x4 frags of 16x16x32
// bf16 MFMA, global_load_lds width=16 staging, K/BK K-iters.
// Tiles: row-major [128][BK], NG=BK/8 granules/row; granule g of row r at
//   slot g^(r&(NG-1)). Staging source col = ((t%NG)^((t/NG)&(NG-1)))*8;
//   frag read slot (c*4+quad)^(l16&(NG-1)).
// BK=64: __launch_bounds__(256,4), 32KB LDS, 4 blocks/CU (qkv/ffn1).
// BK=128: __launch_bounds__(256,2), 64KB LDS — proj/ffn2 (512-block grids
//   cap at 2 blocks/CU anyway; halves barrier drains).
// swz=1: bijective XCD-blocked remap (gridDim.y % 8 == 0 required).
// VF=1 (qkv only; compile-time so VF=0 keeps the proven 64-VGPR codegen):
//   blocks with n0+wn >= 2048 are the V part of fused QKV; each wave's
//   64x64 subtile = one head's (token x hd) tile. Transpose via per-wave
//   LDS (stride 74) and write Vt[b,h,hd,tok] directly; qkv buffer not
//   written for V blocks (nothing reads it).
template <int BK, int VF>
__global__ void __launch_bounds__(256, (BK == 64 ? 4 : 2))
gemm_bt(const ushort_t* __restrict__ A,
        const ushort_t* __restrict__ Bw,
        const float* __restrict__ bias,
        const float* __restrict__ ResF,
        const ushort_t* __restrict__ ResB,
        ushort_t* __restrict__ Cb,
        float* __restrict__ Cf,
        ushort_t* __restrict__ VtT,
        int M, int N, int K, int act, int swz) {
  constexpr int NG = BK / 8;        // granules per row
  constexpr int GM = NG - 1;        // XOR mask
  constexpr int RPP = 2048 / BK;    // rows staged per pass
  constexpr int NP = BK / 16;       // passes per tile
  constexpr int NC = BK / 32;       // k-chunks per K-step
  __shared__ __align__(16) ushort_t sAB[2 * 128 * BK];
  ushort_t* sA = sAB;
  ushort_t* sB = sAB + 128 * BK;
  int t = threadIdx.x;
  int wave = t >> 6, lane = t & 63;
  int quad = lane >> 4, l16 = lane & 15;
  int wm = (wave & 1) * 64, wn = (wave >> 1) * 64;

  int bx = blockIdx.x, by = blockIdx.y;
  if (swz) {
    int lid = by * gridDim.x + bx;
    int xcd = lid & 7, slot = lid >> 3;
    int mchunk = gridDim.y >> 3;           // m-tiles per XCD
    by = xcd * mchunk + slot / gridDim.x;
    bx = slot % gridDim.x;
  }
  int m0 = by * 128, n0 = bx * 128;

  f32x4 zero = {0.f, 0.f, 0.f, 0.f};
  f32x4 acc[4][4];
#pragma unroll
  for (int i = 0; i < 4; i++)
#pragma unroll
    for (int j = 0; j < 4; j++) acc[i][j] = zero;

  int srow = t / NG;
  int scol = ((t & GM) ^ (srow & GM)) * 8;
  const ushort_t* gA = A + (size_t)(m0 + srow) * K + scol;
  const ushort_t* gB = Bw + (size_t)(n0 + srow) * K + scol;

  for (int k0 = 0; k0 < K; k0 += BK) {
#pragma unroll
    for (int p = 0; p < NP; p++) {
      async_ld16(gA + (size_t)p * RPP * K + k0, sA + p * 2048 + wave * 512);
      async_ld16(gB + (size_t)p * RPP * K + k0, sB + p * 2048 + wave * 512);
    }
    __syncthreads();
#pragma unroll
    for (int c = 0; c < NC; c++) {
      int col = (((c * 4 + quad) ^ (l16 & GM)) * 8);
      bf16x8 af[4], bfr[4];
#pragma unroll
      for (int i = 0; i < 4; i++) {
        af[i]  = *(const bf16x8*)(sA + (wm + i * 16 + l16) * BK + col);
        bfr[i] = *(const bf16x8*)(sB + (wn + i * 16 + l16) * BK + col);
      }
#pragma unroll
      for (int mi = 0; mi < 4; mi++)
#pragma unroll
        for (int ni = 0; ni < 4; ni++)
          acc[mi][ni] = __builtin_amdgcn_mfma_f32_16x16x32_bf16(af[mi], bfr[ni], acc[mi][ni], 0, 0, 0);
    }
    __syncthreads();
  }

  // epilogue: C/D layout row = quad*4+r, col = l16 (m89/m91-verified)
  float bv[4];
#pragma unroll
  for (int ni = 0; ni < 4; ni++) bv[ni] = bias[n0 + wn + ni * 16 + l16];

  if (Cf) {
    // f32 output path (ffn2): scalar dword stores, 64B/quad coalesced
#pragma unroll
    for (int mi = 0; mi < 4; mi++) {
      int row = m0 + wm + mi * 16 + quad * 4;
#pragma unroll
      for (int ni = 0; ni < 4; ni++) {
        int col = n0 + wn + ni * 16 + l16;
#pragma unroll
        for (int r = 0; r < 4; r++) {
          size_t idx = (size_t)(row + r) * N + col;
          float vv = acc[mi][ni][r] + bv[ni];
          if (act) vv = gelu_f(vv);
          if (ResB) vv += bf2f(ResB[idx]);
          Cf[idx] = vv;
        }
      }
    }
  } else if (VF && n0 + wn >= 2048) {
    // fused V-transpose epilogue (qkv V region, VF=1 instantiation only).
    int h = (n0 + wn - 2048) >> 6;
    int bb = m0 >> 10;                    // batch
    int bh = bb * 16 + h;
    int tok0 = (m0 & 1023) + wm;
    ushort_t* eb2 = sAB + wave * 2368;    // 32*74 per wave, 4x2368 <= 16384
#pragma unroll
    for (int p = 0; p < 2; p++) {
#pragma unroll
      for (int mm = 0; mm < 2; mm++) {
        int mi = 2 * p + mm;
#pragma unroll
        for (int ni = 0; ni < 4; ni++)
#pragma unroll
          for (int r = 0; r < 4; r++)
            eb2[(mm * 16 + quad * 4 + r) * 74 + ni * 16 + l16] =
                f2bf(acc[mi][ni][r] + bv[ni]);
      }
      // same-wave ds write->read, in-order; WAR preserved per-wave
#pragma unroll
      for (int it = 0; it < 4; it++) {
        int gid = it * 64 + lane;
        int hd = gid >> 2, tg = gid & 3;
        u16x8 o;
#pragma unroll
        for (int j = 0; j < 8; j++) o[j] = eb2[(tg * 8 + j) * 74 + hd];
        *(u16x8*)(VtT + ((size_t)(bh * 64 + hd)) * 1024 + tok0 + p * 32 + tg * 8) = o;
      }
    }
  } else {
    // bf16 output path: per-wave LDS repack (aliases sA; all K-loop reads
    // completed at final barrier) -> 16B/lane stores
    ushort_t* eb = sAB + wave * (16 * 72);
    int lr = lane >> 2, lc = (lane & 3) * 8;
#pragma unroll
    for (int mi = 0; mi < 4; mi++) {
      int row = m0 + wm + mi * 16;
#pragma unroll
      for (int ni = 0; ni < 4; ni++)
#pragma unroll
        for (int r = 0; r < 4; r++) {
          float vv = acc[mi][ni][r] + bv[ni];
          if (act) vv = gelu_f(vv);
          eb[(quad * 4 + r) * 72 + ni * 16 + l16] = f2bf(vv);
        }
      // same-wave ds write->read (in-order); coalesced u16x8 global stores
#pragma unroll
      for (int hc = 0; hc < 64; hc += 32) {
        u16x8 o = *(const u16x8*)(eb + lr * 72 + hc + lc);
        size_t gidx = (size_t)(row + lr) * N + n0 + wn + hc + lc;
        if (ResF) {
          float4 ra = *(const float4*)(ResF + gidx);
          float4 rb = *(const float4*)(ResF + gidx + 4);
          u16x8 o2;
          o2[0] = f2bf(bf2f(o[0]) + ra.x); o2[1] = f2bf(bf2f(o[1]) + ra.y);
          o2[2] = f2bf(bf2f(o[2]) + ra.z); o2[3] = f2bf(bf2f(o[3]) + ra.w);
          o2[4] = f2bf(bf2f(o[4]) + rb.x); o2[5] = f2bf(bf2f(o[5]) + rb.y);
          o2[6] = f2bf(bf2f(o[6]) + rb.z); o2[7] = f2bf(bf2f(o[7]) + rb.w);
          *(u16x8*)(Cb + gidx) = o2;
        } else {
          *(u16x8*)(Cb + gidx) = o;
        }
      }
    }
  }
}

// ---------------- Flash attention, S^T formulation --------------------------
// R15: sP shrunk to per-wave 16x40 ushorts (32 kv + pad), reused across the
// 4 PV kv-quarters. Per slice c: write pk for s=2c,2c+1 (kvq = (s&1)*16 +
// quad*4 + r), b128-read fragment (kvq = quad*8+j), 4 MFMA. Same-wave
// in-order LDS covers write->read and quarter WAR. Stride 40 ushorts = 80B:
// 16B-aligned b128, 2-way (free) banking. LDS 37.9KB -> 4 blocks/CU.
__global__ void __launch_bounds__(256) attn_kernel(const ushort_t* __restrict__ qkv,
                                                   const ushort_t* __restrict__ Vt,
                                                   ushort_t* __restrict__ ctx) {
  __shared__ __align__(16) ushort_t sK[128 * 64];
  __shared__ __align__(16) ushort_t sV[64 * 128];
  __shared__ __align__(16) ushort_t sP[4 * 16 * 40];
  int t = threadIdx.x, wave = t >> 6, lane = t & 63;
  int quad = lane >> 4, l16 = lane & 15;
  int bh = blockIdx.y, b = bh >> 4, h = bh & 15;
  int q0 = blockIdx.x * 64 + wave * 16;
  size_t tokbase = (size_t)b * 1024;
  const float SC2 = 0.18033688011112042f;  // 0.125 * log2(e)

  const ushort_t* qrow = qkv + (tokbase + q0 + l16) * 3072 + h * 64;
  bf16x8 qf0 = *(const bf16x8*)(qrow + quad * 8);
  bf16x8 qf1 = *(const bf16x8*)(qrow + 32 + quad * 8);

  f32x4 zero = {0.f, 0.f, 0.f, 0.f};
  f32x4 O[4];
#pragma unroll
  for (int i = 0; i < 4; i++) O[i] = zero;
  float m2 = -3.0e38f, l = 0.f;

  int kvlK = wave * 32 + (lane >> 3);
  int hdKx = lane & 7;
  ushort_t* pw = sP + wave * (16 * 40);

  for (int kv0 = 0; kv0 < 1024; kv0 += 128) {
#pragma unroll
    for (int j = 0; j < 4; j++) {
      int kvl = kvlK + j * 8;
      int hd = (hdKx ^ (kvl & 7)) * 8;
      async_ld16(qkv + (tokbase + kv0 + kvl) * 3072 + 1024 + h * 64 + hd,
                 sK + wave * 2048 + j * 512);
      int hdv = wave * 16 + j * 4 + (lane >> 4);
      int kvloc = ((lane & 15) ^ (hdv & 15)) * 8;
      async_ld16(Vt + ((size_t)bh * 64 + hdv) * 1024 + kv0 + kvloc,
                 sV + wave * 2048 + j * 512);
    }
    __syncthreads();

    f32x4 st[8];
    __builtin_amdgcn_s_setprio(1);
#pragma unroll
    for (int s = 0; s < 8; s++) {
      bf16x8 kf0 = *(const bf16x8*)(sK + (s * 16 + l16) * 64 + ((quad ^ (l16 & 7)) * 8));
      bf16x8 kf1 = *(const bf16x8*)(sK + (s * 16 + l16) * 64 + (((4 + quad) ^ (l16 & 7)) * 8));
      st[s] = __builtin_amdgcn_mfma_f32_16x16x32_bf16(kf0, qf0, zero, 0, 0, 0);
      st[s] = __builtin_amdgcn_mfma_f32_16x16x32_bf16(kf1, qf1, st[s], 0, 0, 0);
    }
    __builtin_amdgcn_s_setprio(0);
    f32x4 mx4 = st[0];
#pragma unroll
    for (int s = 1; s < 8; s++)
#pragma unroll
      for (int r = 0; r < 4; r++) mx4[r] = fmaxf(mx4[r], st[s][r]);
    float mx = fmaxf(fmaxf(mx4[0], mx4[1]), fmaxf(mx4[2], mx4[3]));
    mx = fmaxf(mx, __shfl_xor(mx, 16));
    mx = fmaxf(mx, __shfl_xor(mx, 32));
    float mx2 = mx * SC2;
    if (!__all(mx2 - m2 <= 8.0f)) {
      float mnew2 = fmaxf(m2, mx2);
      float alpha = fast_exp2(m2 - mnew2);
      m2 = mnew2;
      l *= alpha;
#pragma unroll
      for (int ti = 0; ti < 4; ti++)
#pragma unroll
        for (int r = 0; r < 4; r++) O[ti][r] *= alpha;
    }
    float rs = 0.f;
#pragma unroll
    for (int s = 0; s < 8; s++)
#pragma unroll
      for (int r = 0; r < 4; r++) {
        st[s][r] = fast_exp2(fmaf(st[s][r], SC2, -m2));
        rs += st[s][r];
      }
    rs += __shfl_xor(rs, 16);
    rs += __shfl_xor(rs, 32);
    l += rs;
    // PV: kv-quarter c uses sP rows l16 (stride 40 ushorts): write s=2c,2c+1
    // (kvq=(s&1)*16+quad*4+r), read kvq=quad*8+j. Same-wave in-order LDS.
    __builtin_amdgcn_s_setprio(1);
#pragma unroll
    for (int c = 0; c < 4; c++) {
#pragma unroll
      for (int e = 0; e < 2; e++) {
        int s = 2 * c + e;
        uint2 pk;
        pk.x = __builtin_amdgcn_perm(__float_as_uint(st[s][1]), __float_as_uint(st[s][0]), 0x07060302u);
        pk.y = __builtin_amdgcn_perm(__float_as_uint(st[s][3]), __float_as_uint(st[s][2]), 0x07060302u);
        *(uint2*)(pw + l16 * 40 + e * 16 + quad * 4) = pk;
      }
      bf16x8 pf = *(const bf16x8*)(pw + l16 * 40 + quad * 8);
#pragma unroll
      for (int ti = 0; ti < 4; ti++) {
        bf16x8 vf = *(const bf16x8*)(sV + (ti * 16 + l16) * 128 + (((c * 4 + quad) ^ l16) * 8));
        O[ti] = __builtin_amdgcn_mfma_f32_16x16x32_bf16(vf, pf, O[ti], 0, 0, 0);
      }
    }
    __builtin_amdgcn_s_setprio(0);
    __syncthreads();
  }
  float inv = 1.0f / l;
  ushort_t* cb = ctx + (tokbase + q0 + l16) * 1024 + h * 64;
#pragma unroll
  for (int ti = 0; ti < 4; ti++) {
    uint2 pk;
    pk.x = (unsigned int)f2bf(O[ti][0] * inv) | ((unsigned int)f2bf(O[ti][1] * inv) << 16);
    pk.y = (unsigned int)f2bf(O[ti][2] * inv) | ((unsigned int)f2bf(O[ti][3] * inv) << 16);
    *(uint2*)(cb + ti * 16 + quad * 4) = pk;
  }
}

extern "C" void kernel_launch(void* const* d_in, const int* in_sizes, int n_in,
                              void* d_out, int out_size, void* d_ws, size_t ws_size,
                              hipStream_t stream) {
  (void)in_sizes; (void)n_in; (void)out_size; (void)ws_size;
  const float* x     = (const float*)d_in[0];
  const float* ln1g  = (const float*)d_in[1];
  const float* ln1b  = (const float*)d_in[2];
  const float* ln2g  = (const float*)d_in[3];
  const float* ln2b  = (const float*)d_in[4];
  const float* Wqkv  = (const float*)d_in[5];
  const float* bqkv  = (const float*)d_in[6];
  const float* Wproj = (const float*)d_in[7];
  const float* bproj = (const float*)d_in[8];
  const float* W1    = (const float*)d_in[9];
  const float* b1    = (const float*)d_in[10];
  const float* W2    = (const float*)d_in[11];
  const float* b2    = (const float*)d_in[12];
  float* out = (float*)d_out;
  char* ws = (char*)d_ws;
  const size_t MB = 1u << 20;
  ushort_t* Wqkv_b  = (ushort_t*)(ws + 0);
  ushort_t* Wproj_b = (ushort_t*)(ws + 6 * MB);
  ushort_t* h1      = (ushort_t*)(ws + 8 * MB);
  ushort_t* qkv     = (ushort_t*)(ws + 24 * MB);
  ushort_t* Vt      = (ushort_t*)(ws + 72 * MB);
  ushort_t* ctx     = (ushort_t*)(ws + 8 * MB);
  ushort_t* out1    = (ushort_t*)(ws + 24 * MB);
  ushort_t* W1_b    = (ushort_t*)(ws + 0);
  ushort_t* h2      = (ushort_t*)(ws + 8 * MB);
  ushort_t* ff1     = (ushort_t*)(ws + 40 * MB);
  ushort_t* W2_b    = (ushort_t*)(ws + 0);

  cvt_f32_bf16_2<<<2048, 256, 0, stream>>>(Wqkv, Wqkv_b, 3 * 1024 * 1024,
                                           Wproj, Wproj_b, 1024 * 1024);
  ln_f32<<<2048, 256, 0, stream>>>(x, ln1g, ln1b, h1);
  gemm_bt<64, 1><<<dim3(24, 64), 256, 0, stream>>>(h1, Wqkv_b, bqkv, nullptr, nullptr, qkv, nullptr, Vt, 8192, 3072, 1024, 0, 0);
  attn_kernel<<<dim3(16, 128), 256, 0, stream>>>(qkv, Vt, ctx);
  gemm_bt<128, 0><<<dim3(8, 64), 256, 0, stream>>>(ctx, Wproj_b, bproj, x, nullptr, out1, nullptr, nullptr, 8192, 1024, 1024, 0, 0);
  cvt_f32_bf16<<<2048, 256, 0, stream>>>(W1, W1_b, 4 * 1024 * 1024);
  ln_bf16<<<2048, 256, 0, stream>>>(out1, ln2g, ln2b, h2);
  gemm_bt<64, 0><<<dim3(32, 64), 256, 0, stream>>>(h2, W1_b, b1, nullptr, nullptr, ff1, nullptr, nullptr, 8192, 4096, 1024, 1, 0);
  cvt_f32_bf16<<<2048, 256, 0, stream>>>(W2, W2_b, 4 * 1024 * 1024);
  gemm_bt<128, 0><<<dim3(8, 64), 256, 0, stream>>>(ff1, W2_b, b2, nullptr, out1, nullptr, out, nullptr, 8192, 1024, 4096, 1, 1);
}

// Round 9
// 453.499 us; speedup vs baseline: 1.2900x; 1.0487x over previous
//
#include <hip/hip_runtime.h>

// Problem: B=8, N=1024, D=1024, H=16, HD=64, FF=4096. Tokens M = 8192.
// Inputs f32, OUTPUT f32. Internals bf16, f32 accumulation.
// Round 16: (1) XCD swizzle on ffn1 (FETCH 74MB vs 24MB compulsory, same
// A-panel re-fetch signature as ffn2 pre-R8; grid 32x64 qualifies).
// (2) If ws_size >= 120MB: W1_b/W2_b relocated to 104/112MB (dead regions)
// and all 4 weight cvts merged into ONE up-front launch — removes the two
// mid-pipeline cvt serialization bubbles. Host-side ws_size branch keeps
// the old path as fallback. Everything else frozen at R15 config.

typedef unsigned short ushort_t;
typedef __bf16 bf16x8 __attribute__((ext_vector_type(8)));
typedef float f32x4 __attribute__((ext_vector_type(4)));
typedef unsigned short u16x8 __attribute__((ext_vector_type(8)));

__device__ __forceinline__ void async_ld16(const void* g, void* l) {
  // global -> LDS direct, 16B per lane. LDS dst is wave-uniform base; HW
  // writes base + lane*16.
  __builtin_amdgcn_global_load_lds(
      (void __attribute__((address_space(1)))*)const_cast<void*>(g),
      (void __attribute__((address_space(3)))*)l, 16, 0, 0);
}

__device__ __forceinline__ float bf2f(ushort_t h) {
  union { unsigned int u; float f; } v;
  v.u = ((unsigned int)h) << 16;
  return v.f;
}
__device__ __forceinline__ ushort_t f2bf(float f) {
  union { float f; unsigned int u; } v;
  v.f = f;
  unsigned int r = v.u + 0x7FFFu + ((v.u >> 16) & 1u);  // RNE
  return (ushort_t)(r >> 16);
}
// 2^x via HW v_exp_f32 (D = 2^S0 per ISA); guarded fallback keeps semantics.
__device__ __forceinline__ float fast_exp2(float x) {
#if __has_builtin(__builtin_amdgcn_exp2f)
  return __builtin_amdgcn_exp2f(x);
#else
  return __expf(x * 0.6931471805599453f);
#endif
}
// tanh-form GELU (~3e-4 dev from exact erf; 0.078 threshold headroom)
__device__ __forceinline__ float gelu_f(float x) {
  float y = 0.7978845608028654f * (x + 0.044715f * x * x * x);
  float e = __expf(2.0f * y);
  float t = 1.0f - 2.0f / (e + 1.0f);
  return 0.5f * x * (1.0f + t);
}

// ---------------- f32 -> bf16 weight conversion (8 elems/thread) ------------
__global__ void __launch_bounds__(256) cvt_f32_bf16(const float* __restrict__ src,
                                                    ushort_t* __restrict__ dst, int n) {
  int i = (blockIdx.x * 256 + threadIdx.x) * 8;
  if (i >= n) return;
  float4 a = *(const float4*)(src + i);
  float4 b = *(const float4*)(src + i + 4);
  u16x8 o;
  o[0] = f2bf(a.x); o[1] = f2bf(a.y); o[2] = f2bf(a.z); o[3] = f2bf(a.w);
  o[4] = f2bf(b.x); o[5] = f2bf(b.y); o[6] = f2bf(b.z); o[7] = f2bf(b.w);
  *(u16x8*)(dst + i) = o;
}

// two-buffer variant: one launch for Wqkv (n0) + Wproj (n1), non-aliasing dsts
__global__ void __launch_bounds__(256) cvt_f32_bf16_2(const float* __restrict__ s0,
                                                      ushort_t* __restrict__ d0, int n0,
                                                      const float* __restrict__ s1,
                                                      ushort_t* __restrict__ d1, int n1) {
  int i = (blockIdx.x * 256 + threadIdx.x) * 8;
  const float* src;
  ushort_t* dst;
  if (i < n0) {
    src = s0 + i; dst = d0 + i;
  } else {
    int j = i - n0;
    if (j >= n1) return;
    src = s1 + j; dst = d1 + j;
  }
  float4 a = *(const float4*)(src);
  float4 b = *(const float4*)(src + 4);
  u16x8 o;
  o[0] = f2bf(a.x); o[1] = f2bf(a.y); o[2] = f2bf(a.z); o[3] = f2bf(a.w);
  o[4] = f2bf(b.x); o[5] = f2bf(b.y); o[6] = f2bf(b.z); o[7] = f2bf(b.w);
  *(u16x8*)dst = o;
}

// four-buffer variant: all weights in one up-front launch (big-ws path)
__global__ void __launch_bounds__(256) cvt_f32_bf16_4(
    const float* __restrict__ s0, ushort_t* __restrict__ d0, int n0,
    const float* __restrict__ s1, ushort_t* __restrict__ d1, int n1,
    const float* __restrict__ s2, ushort_t* __restrict__ d2, int n2,
    const float* __restrict__ s3, ushort_t* __restrict__ d3, int n3) {
  int i = (blockIdx.x * 256 + threadIdx.x) * 8;
  const float* src;
  ushort_t* dst;
  if (i < n0) { src = s0 + i; dst = d0 + i; }
  else {
    i -= n0;
    if (i < n1) { src = s1 + i; dst = d1 + i; }
    else {
      i -= n1;
      if (i < n2) { src = s2 + i; dst = d2 + i; }
      else {
        i -= n2;
        if (i >= n3) return;
        src = s3 + i; dst = d3 + i;
      }
    }
  }
  float4 a = *(const float4*)(src);
  float4 b = *(const float4*)(src + 4);
  u16x8 o;
  o[0] = f2bf(a.x); o[1] = f2bf(a.y); o[2] = f2bf(a.z); o[3] = f2bf(a.w);
  o[4] = f2bf(b.x); o[5] = f2bf(b.y); o[6] = f2bf(b.z); o[7] = f2bf(b.w);
  *(u16x8*)dst = o;
}

// ---------------- LayerNorm (f32 in, bf16 out): 1 wave per token ------------
__global__ void __launch_bounds__(256) ln_f32(const float* __restrict__ X,
                                              const float* __restrict__ G,
                                              const float* __restrict__ Bb,
                                              ushort_t* __restrict__ Y) {
  int tok = blockIdx.x * 4 + (threadIdx.x >> 6);
  int lane = threadIdx.x & 63;
  const float* xr = X + (size_t)tok * 1024 + lane * 16;
  float v[16];
#pragma unroll
  for (int c = 0; c < 4; c++) {
    float4 a = *(const float4*)(xr + c * 4);
    v[c * 4 + 0] = a.x; v[c * 4 + 1] = a.y; v[c * 4 + 2] = a.z; v[c * 4 + 3] = a.w;
  }
  float s = 0.f, ss = 0.f;
#pragma unroll
  for (int j = 0; j < 16; j++) { s += v[j]; ss += v[j] * v[j]; }
#pragma unroll
  for (int off = 32; off >= 1; off >>= 1) {
    s += __shfl_xor(s, off);
    ss += __shfl_xor(ss, off);
  }
  float mu = s * (1.f / 1024.f);
  float var = ss * (1.f / 1024.f) - mu * mu;
  float rs = rsqrtf(var + 1e-5f);
  u16x8 o0, o1;
#pragma unroll
  for (int c = 0; c < 4; c++) {
    float4 g = *(const float4*)(G + lane * 16 + c * 4);
    float4 bb = *(const float4*)(Bb + lane * 16 + c * 4);
    ushort_t* op = (c < 2) ? (ushort_t*)&o0 : (ushort_t*)&o1;
    int base = (c & 1) * 4;
    op[base + 0] = f2bf((v[c * 4 + 0] - mu) * rs * g.x + bb.x);
    op[base + 1] = f2bf((v[c * 4 + 1] - mu) * rs * g.y + bb.y);
    op[base + 2] = f2bf((v[c * 4 + 2] - mu) * rs * g.z + bb.z);
    op[base + 3] = f2bf((v[c * 4 + 3] - mu) * rs * g.w + bb.w);
  }
  ushort_t* yr = Y + (size_t)tok * 1024 + lane * 16;
  *(u16x8*)yr = o0;
  *(u16x8*)(yr + 8) = o1;
}

// ---------------- LayerNorm (bf16 in, bf16 out): 1 wave per token -----------
__global__ void __launch_bounds__(256) ln_bf16(const ushort_t* __restrict__ X,
                                               const float* __restrict__ G,
                                               const float* __restrict__ Bb,
                                               ushort_t* __restrict__ Y) {
  int tok = blockIdx.x * 4 + (threadIdx.x >> 6);
  int lane = threadIdx.x & 63;
  const ushort_t* xr = X + (size_t)tok * 1024 + lane * 16;
  u16x8 x0 = *(const u16x8*)xr;
  u16x8 x1 = *(const u16x8*)(xr + 8);
  float v[16];
  float s = 0.f, ss = 0.f;
#pragma unroll
  for (int j = 0; j < 8; j++) { v[j] = bf2f(x0[j]); v[8 + j] = bf2f(x1[j]); }
#pragma unroll
  for (int j = 0; j < 16; j++) { s += v[j]; ss += v[j] * v[j]; }
#pragma unroll
  for (int off = 32; off >= 1; off >>= 1) {
    s += __shfl_xor(s, off);
    ss += __shfl_xor(ss, off);
  }
  float mu = s * (1.f / 1024.f);
  float var = ss * (1.f / 1024.f) - mu * mu;
  float rs = rsqrtf(var + 1e-5f);
  u16x8 o0, o1;
#pragma unroll
  for (int c = 0; c < 4; c++) {
    float4 g = *(const float4*)(G + lane * 16 + c * 4);
    float4 bb = *(const float4*)(Bb + lane * 16 + c * 4);
    ushort_t* op = (c < 2) ? (ushort_t*)&o0 : (ushort_t*)&o1;
    int base = (c & 1) * 4;
    op[base + 0] = f2bf((v[c * 4 + 0] - mu) * rs * g.x + bb.x);
    op[base + 1] = f2bf((v[c * 4 + 1] - mu) * rs * g.y + bb.y);
    op[base + 2] = f2bf((v[c * 4 + 2] - mu) * rs * g.z + bb.z);
    op[base + 3] = f2bf((v[c * 4 + 3] - mu) * rs * g.w + bb.w);
  }
  ushort_t* yr = Y + (size_t)tok * 1024 + lane * 16;
  *(u16x8*)yr = o0;
  *(u16x8*)(yr + 8) = o1;
}

// ---------------- GEMM: C[M,N] = act(A[M,K] @ B[N,K]^T + bias) (+Res) -------
// 128x128 tile, template BK in {64,128}, 4 waves 2x2, 4x4 frags of 16x16x32
// bf16 MFMA, global_load_lds width=16 staging, K/BK K-iters.
// Tiles: row-major [128][BK], NG=BK/8 granules/row; granule g of row r at
//   slot g^(r&(NG-1)). Staging source col = ((t%NG)^((t/NG)&(NG-1)))*8;
//   frag read slot (c*4+quad)^(l16&(NG-1)).
// BK=64: __launch_bounds__(256,4), 32KB LDS, 4 blocks/CU (qkv/ffn1).
// BK=128: __launch_bounds__(256,2), 64KB LDS — proj/ffn2 (512-block grids
//   cap at 2 blocks/CU anyway; halves barrier drains).
// swz=1: bijective XCD-blocked remap (gridDim.y % 8 == 0 required). Used by
//   ffn1 + ffn2 (measured 3x A-panel over-fetch without it).
// VF=1 (qkv only; compile-time so VF=0 keeps the proven 64-VGPR codegen):
//   blocks with n0+wn >= 2048 are the V part of fused QKV; each wave's
//   64x64 subtile = one head's (token x hd) tile. Transpose via per-wave
//   LDS (stride 74) and write Vt[b,h,hd,tok] directly; qkv buffer not
//   written for V blocks (nothing reads it).
template <int BK, int VF>
__global__ void __launch_bounds__(256, (BK == 64 ? 4 : 2))
gemm_bt(const ushort_t* __restrict__ A,
        const ushort_t* __restrict__ Bw,
        const float* __restrict__ bias,
        const float* __restrict__ ResF,
        const ushort_t* __restrict__ ResB,
        ushort_t* __restrict__ Cb,
        float* __restrict__ Cf,
        ushort_t* __restrict__ VtT,
        int M, int N, int K, int act, int swz) {
  constexpr int NG = BK / 8;        // granules per row
  constexpr int GM = NG - 1;        // XOR mask
  constexpr int RPP = 2048 / BK;    // rows staged per pass
  constexpr int NP = BK / 16;       // passes per tile
  constexpr int NC = BK / 32;       // k-chunks per K-step
  __shared__ __align__(16) ushort_t sAB[2 * 128 * BK];
  ushort_t* sA = sAB;
  ushort_t* sB = sAB + 128 * BK;
  int t = threadIdx.x;
  int wave = t >> 6, lane = t & 63;
  int quad = lane >> 4, l16 = lane & 15;
  int wm = (wave & 1) * 64, wn = (wave >> 1) * 64;

  int bx = blockIdx.x, by = blockIdx.y;
  if (swz) {
    int lid = by * gridDim.x + bx;
    int xcd = lid & 7, slot = lid >> 3;
    int mchunk = gridDim.y >> 3;           // m-tiles per XCD
    by = xcd * mchunk + slot / gridDim.x;
    bx = slot % gridDim.x;
  }
  int m0 = by * 128, n0 = bx * 128;

  f32x4 zero = {0.f, 0.f, 0.f, 0.f};
  f32x4 acc[4][4];
#pragma unroll
  for (int i = 0; i < 4; i++)
#pragma unroll
    for (int j = 0; j < 4; j++) acc[i][j] = zero;

  int srow = t / NG;
  int scol = ((t & GM) ^ (srow & GM)) * 8;
  const ushort_t* gA = A + (size_t)(m0 + srow) * K + scol;
  const ushort_t* gB = Bw + (size_t)(n0 + srow) * K + scol;

  for (int k0 = 0; k0 < K; k0 += BK) {
#pragma unroll
    for (int p = 0; p < NP; p++) {
      async_ld16(gA + (size_t)p * RPP * K + k0, sA + p * 2048 + wave * 512);
      async_ld16(gB + (size_t)p * RPP * K + k0, sB + p * 2048 + wave * 512);
    }
    __syncthreads();
#pragma unroll
    for (int c = 0; c < NC; c++) {
      int col = (((c * 4 + quad) ^ (l16 & GM)) * 8);
      bf16x8 af[4], bfr[4];
#pragma unroll
      for (int i = 0; i < 4; i++) {
        af[i]  = *(const bf16x8*)(sA + (wm + i * 16 + l16) * BK + col);
        bfr[i] = *(const bf16x8*)(sB + (wn + i * 16 + l16) * BK + col);
      }
#pragma unroll
      for (int mi = 0; mi < 4; mi++)
#pragma unroll
        for (int ni = 0; ni < 4; ni++)
          acc[mi][ni] = __builtin_amdgcn_mfma_f32_16x16x32_bf16(af[mi], bfr[ni], acc[mi][ni], 0, 0, 0);
    }
    __syncthreads();
  }

  // epilogue: C/D layout row = quad*4+r, col = l16 (m89/m91-verified)
  float bv[4];
#pragma unroll
  for (int ni = 0; ni < 4; ni++) bv[ni] = bias[n0 + wn + ni * 16 + l16];

  if (Cf) {
    // f32 output path (ffn2): scalar dword stores, 64B/quad coalesced
#pragma unroll
    for (int mi = 0; mi < 4; mi++) {
      int row = m0 + wm + mi * 16 + quad * 4;
#pragma unroll
      for (int ni = 0; ni < 4; ni++) {
        int col = n0 + wn + ni * 16 + l16;
#pragma unroll
        for (int r = 0; r < 4; r++) {
          size_t idx = (size_t)(row + r) * N + col;
          float vv = acc[mi][ni][r] + bv[ni];
          if (act) vv = gelu_f(vv);
          if (ResB) vv += bf2f(ResB[idx]);
          Cf[idx] = vv;
        }
      }
    }
  } else if (VF && n0 + wn >= 2048) {
    // fused V-transpose epilogue (qkv V region, VF=1 instantiation only).
    int h = (n0 + wn - 2048) >> 6;
    int bb = m0 >> 10;                    // batch
    int bh = bb * 16 + h;
    int tok0 = (m0 & 1023) + wm;
    ushort_t* eb2 = sAB + wave * 2368;    // 32*74 per wave, 4x2368 <= 16384
#pragma unroll
    for (int p = 0; p < 2; p++) {
#pragma unroll
      for (int mm = 0; mm < 2; mm++) {
        int mi = 2 * p + mm;
#pragma unroll
        for (int ni = 0; ni < 4; ni++)
#pragma unroll
          for (int r = 0; r < 4; r++)
            eb2[(mm * 16 + quad * 4 + r) * 74 + ni * 16 + l16] =
                f2bf(acc[mi][ni][r] + bv[ni]);
      }
      // same-wave ds write->read, in-order; WAR preserved per-wave
#pragma unroll
      for (int it = 0; it < 4; it++) {
        int gid = it * 64 + lane;
        int hd = gid >> 2, tg = gid & 3;
        u16x8 o;
#pragma unroll
        for (int j = 0; j < 8; j++) o[j] = eb2[(tg * 8 + j) * 74 + hd];
        *(u16x8*)(VtT + ((size_t)(bh * 64 + hd)) * 1024 + tok0 + p * 32 + tg * 8) = o;
      }
    }
  } else {
    // bf16 output path: per-wave LDS repack (aliases sA; all K-loop reads
    // completed at final barrier) -> 16B/lane stores
    ushort_t* eb = sAB + wave * (16 * 72);
    int lr = lane >> 2, lc = (lane & 3) * 8;
#pragma unroll
    for (int mi = 0; mi < 4; mi++) {
      int row = m0 + wm + mi * 16;
#pragma unroll
      for (int ni = 0; ni < 4; ni++)
#pragma unroll
        for (int r = 0; r < 4; r++) {
          float vv = acc[mi][ni][r] + bv[ni];
          if (act) vv = gelu_f(vv);
          eb[(quad * 4 + r) * 72 + ni * 16 + l16] = f2bf(vv);
        }
      // same-wave ds write->read (in-order); coalesced u16x8 global stores
#pragma unroll
      for (int hc = 0; hc < 64; hc += 32) {
        u16x8 o = *(const u16x8*)(eb + lr * 72 + hc + lc);
        size_t gidx = (size_t)(row + lr) * N + n0 + wn + hc + lc;
        if (ResF) {
          float4 ra = *(const float4*)(ResF + gidx);
          float4 rb = *(const float4*)(ResF + gidx + 4);
          u16x8 o2;
          o2[0] = f2bf(bf2f(o[0]) + ra.x); o2[1] = f2bf(bf2f(o[1]) + ra.y);
          o2[2] = f2bf(bf2f(o[2]) + ra.z); o2[3] = f2bf(bf2f(o[3]) + ra.w);
          o2[4] = f2bf(bf2f(o[4]) + rb.x); o2[5] = f2bf(bf2f(o[5]) + rb.y);
          o2[6] = f2bf(bf2f(o[6]) + rb.z); o2[7] = f2bf(bf2f(o[7]) + rb.w);
          *(u16x8*)(Cb + gidx) = o2;
        } else {
          *(u16x8*)(Cb + gidx) = o;
        }
      }
    }
  }
}

// ---------------- Flash attention, S^T formulation (R15 version) ------------
__global__ void __launch_bounds__(256) attn_kernel(const ushort_t* __restrict__ qkv,
                                                   const ushort_t* __restrict__ Vt,
                                                   ushort_t* __restrict__ ctx) {
  __shared__ __align__(16) ushort_t sK[128 * 64];
  __shared__ __align__(16) ushort_t sV[64 * 128];
  __shared__ __align__(16) ushort_t sP[4 * 16 * 40];
  int t = threadIdx.x, wave = t >> 6, lane = t & 63;
  int quad = lane >> 4, l16 = lane & 15;
  int bh = blockIdx.y, b = bh >> 4, h = bh & 15;
  int q0 = blockIdx.x * 64 + wave * 16;
  size_t tokbase = (size_t)b * 1024;
  const float SC2 = 0.18033688011112042f;  // 0.125 * log2(e)

  const ushort_t* qrow = qkv + (tokbase + q0 + l16) * 3072 + h * 64;
  bf16x8 qf0 = *(const bf16x8*)(qrow + quad * 8);
  bf16x8 qf1 = *(const bf16x8*)(qrow + 32 + quad * 8);

  f32x4 zero = {0.f, 0.f, 0.f, 0.f};
  f32x4 O[4];
#pragma unroll
  for (int i = 0; i < 4; i++) O[i] = zero;
  float m2 = -3.0e38f, l = 0.f;

  int kvlK = wave * 32 + (lane >> 3);
  int hdKx = lane & 7;
  ushort_t* pw = sP + wave * (16 * 40);

  for (int kv0 = 0; kv0 < 1024; kv0 += 128) {
#pragma unroll
    for (int j = 0; j < 4; j++) {
      int kvl = kvlK + j * 8;
      int hd = (hdKx ^ (kvl & 7)) * 8;
      async_ld16(qkv + (tokbase + kv0 + kvl) * 3072 + 1024 + h * 64 + hd,
                 sK + wave * 2048 + j * 512);
      int hdv = wave * 16 + j * 4 + (lane >> 4);
      int kvloc = ((lane & 15) ^ (hdv & 15)) * 8;
      async_ld16(Vt + ((size_t)bh * 64 + hdv) * 1024 + kv0 + kvloc,
                 sV + wave * 2048 + j * 512);
    }
    __syncthreads();

    f32x4 st[8];
    __builtin_amdgcn_s_setprio(1);
#pragma unroll
    for (int s = 0; s < 8; s++) {
      bf16x8 kf0 = *(const bf16x8*)(sK + (s * 16 + l16) * 64 + ((quad ^ (l16 & 7)) * 8));
      bf16x8 kf1 = *(const bf16x8*)(sK + (s * 16 + l16) * 64 + (((4 + quad) ^ (l16 & 7)) * 8));
      st[s] = __builtin_amdgcn_mfma_f32_16x16x32_bf16(kf0, qf0, zero, 0, 0, 0);
      st[s] = __builtin_amdgcn_mfma_f32_16x16x32_bf16(kf1, qf1, st[s], 0, 0, 0);
    }
    __builtin_amdgcn_s_setprio(0);
    f32x4 mx4 = st[0];
#pragma unroll
    for (int s = 1; s < 8; s++)
#pragma unroll
      for (int r = 0; r < 4; r++) mx4[r] = fmaxf(mx4[r], st[s][r]);
    float mx = fmaxf(fmaxf(mx4[0], mx4[1]), fmaxf(mx4[2], mx4[3]));
    mx = fmaxf(mx, __shfl_xor(mx, 16));
    mx = fmaxf(mx, __shfl_xor(mx, 32));
    float mx2 = mx * SC2;
    if (!__all(mx2 - m2 <= 8.0f)) {
      float mnew2 = fmaxf(m2, mx2);
      float alpha = fast_exp2(m2 - mnew2);
      m2 = mnew2;
      l *= alpha;
#pragma unroll
      for (int ti = 0; ti < 4; ti++)
#pragma unroll
        for (int r = 0; r < 4; r++) O[ti][r] *= alpha;
    }
    float rs = 0.f;
#pragma unroll
    for (int s = 0; s < 8; s++)
#pragma unroll
      for (int r = 0; r < 4; r++) {
        st[s][r] = fast_exp2(fmaf(st[s][r], SC2, -m2));
        rs += st[s][r];
      }
    rs += __shfl_xor(rs, 16);
    rs += __shfl_xor(rs, 32);
    l += rs;
    // PV: kv-quarter c uses sP rows l16 (stride 40 ushorts): write s=2c,2c+1
    // (kvq=(s&1)*16+quad*4+r), read kvq=quad*8+j. Same-wave in-order LDS.
    __builtin_amdgcn_s_setprio(1);
#pragma unroll
    for (int c = 0; c < 4; c++) {
#pragma unroll
      for (int e = 0; e < 2; e++) {
        int s = 2 * c + e;
        uint2 pk;
        pk.x = __builtin_amdgcn_perm(__float_as_uint(st[s][1]), __float_as_uint(st[s][0]), 0x07060302u);
        pk.y = __builtin_amdgcn_perm(__float_as_uint(st[s][3]), __float_as_uint(st[s][2]), 0x07060302u);
        *(uint2*)(pw + l16 * 40 + e * 16 + quad * 4) = pk;
      }
      bf16x8 pf = *(const bf16x8*)(pw + l16 * 40 + quad * 8);
#pragma unroll
      for (int ti = 0; ti < 4; ti++) {
        bf16x8 vf = *(const bf16x8*)(sV + (ti * 16 + l16) * 128 + (((c * 4 + quad) ^ l16) * 8));
        O[ti] = __builtin_amdgcn_mfma_f32_16x16x32_bf16(vf, pf, O[ti], 0, 0, 0);
      }
    }
    __builtin_amdgcn_s_setprio(0);
    __syncthreads();
  }
  float inv = 1.0f / l;
  ushort_t* cb = ctx + (tokbase + q0 + l16) * 1024 + h * 64;
#pragma unroll
  for (int ti = 0; ti < 4; ti++) {
    uint2 pk;
    pk.x = (unsigned int)f2bf(O[ti][0] * inv) | ((unsigned int)f2bf(O[ti][1] * inv) << 16);
    pk.y = (unsigned int)f2bf(O[ti][2] * inv) | ((unsigned int)f2bf(O[ti][3] * inv) << 16);
    *(uint2*)(cb + ti * 16 + quad * 4) = pk;
  }
}

extern "C" void kernel_launch(void* const* d_in, const int* in_sizes, int n_in,
                              void* d_out, int out_size, void* d_ws, size_t ws_size,
                              hipStream_t stream) {
  (void)in_sizes; (void)n_in; (void)out_size;
  const float* x     = (const float*)d_in[0];
  const float* ln1g  = (const float*)d_in[1];
  const float* ln1b  = (const float*)d_in[2];
  const float* ln2g  = (const float*)d_in[3];
  const float* ln2b  = (const float*)d_in[4];
  const float* Wqkv  = (const float*)d_in[5];
  const float* bqkv  = (const float*)d_in[6];
  const float* Wproj = (const float*)d_in[7];
  const float* bproj = (const float*)d_in[8];
  const float* W1    = (const float*)d_in[9];
  const float* b1    = (const float*)d_in[10];
  const float* W2    = (const float*)d_in[11];
  const float* b2    = (const float*)d_in[12];
  float* out = (float*)d_out;
  char* ws = (char*)d_ws;
  const size_t MB = 1u << 20;
  ushort_t* Wqkv_b  = (ushort_t*)(ws + 0);
  ushort_t* Wproj_b = (ushort_t*)(ws + 6 * MB);
  ushort_t* h1      = (ushort_t*)(ws + 8 * MB);
  ushort_t* qkv     = (ushort_t*)(ws + 24 * MB);
  ushort_t* Vt      = (ushort_t*)(ws + 72 * MB);
  ushort_t* ctx     = (ushort_t*)(ws + 8 * MB);
  ushort_t* out1    = (ushort_t*)(ws + 24 * MB);
  ushort_t* h2      = (ushort_t*)(ws + 8 * MB);
  ushort_t* ff1     = (ushort_t*)(ws + 40 * MB);

  if (ws_size >= 120 * MB) {
    // big-ws path: W1_b/W2_b in dedicated regions (104/112MB, dead in the
    // aliased layout); ALL weight cvts in one up-front launch -> no
    // mid-pipeline cvt bubbles.
    ushort_t* W1_b = (ushort_t*)(ws + 104 * MB);
    ushort_t* W2_b = (ushort_t*)(ws + 112 * MB);
    cvt_f32_bf16_4<<<6144, 256, 0, stream>>>(
        Wqkv, Wqkv_b, 3 * 1024 * 1024, Wproj, Wproj_b, 1024 * 1024,
        W1, W1_b, 4 * 1024 * 1024, W2, W2_b, 4 * 1024 * 1024);
    ln_f32<<<2048, 256, 0, stream>>>(x, ln1g, ln1b, h1);
    gemm_bt<64, 1><<<dim3(24, 64), 256, 0, stream>>>(h1, Wqkv_b, bqkv, nullptr, nullptr, qkv, nullptr, Vt, 8192, 3072, 1024, 0, 0);
    attn_kernel<<<dim3(16, 128), 256, 0, stream>>>(qkv, Vt, ctx);
    gemm_bt<128, 0><<<dim3(8, 64), 256, 0, stream>>>(ctx, Wproj_b, bproj, x, nullptr, out1, nullptr, nullptr, 8192, 1024, 1024, 0, 0);
    ln_bf16<<<2048, 256, 0, stream>>>(out1, ln2g, ln2b, h2);
    gemm_bt<64, 0><<<dim3(32, 64), 256, 0, stream>>>(h2, W1_b, b1, nullptr, nullptr, ff1, nullptr, nullptr, 8192, 4096, 1024, 1, 1);
    gemm_bt<128, 0><<<dim3(8, 64), 256, 0, stream>>>(ff1, W2_b, b2, nullptr, out1, nullptr, out, nullptr, 8192, 1024, 4096, 1, 1);
  } else {
    // fallback: aliased W1_b/W2_b at offset 0, cvts interleaved (R15 layout)
    ushort_t* W1_b = (ushort_t*)(ws + 0);
    ushort_t* W2_b = (ushort_t*)(ws + 0);
    cvt_f32_bf16_2<<<2048, 256, 0, stream>>>(Wqkv, Wqkv_b, 3 * 1024 * 1024,
                                             Wproj, Wproj_b, 1024 * 1024);
    ln_f32<<<2048, 256, 0, stream>>>(x, ln1g, ln1b, h1);
    gemm_bt<64, 1><<<dim3(24, 64), 256, 0, stream>>>(h1, Wqkv_b, bqkv, nullptr, nullptr, qkv, nullptr, Vt, 8192, 3072, 1024, 0, 0);
    attn_kernel<<<dim3(16, 128), 256, 0, stream>>>(qkv, Vt, ctx);
    gemm_bt<128, 0><<<dim3(8, 64), 256, 0, stream>>>(ctx, Wproj_b, bproj, x, nullptr, out1, nullptr, nullptr, 8192, 1024, 1024, 0, 0);
    cvt_f32_bf16<<<2048, 256, 0, stream>>>(W1, W1_b, 4 * 1024 * 1024);
    ln_bf16<<<2048, 256, 0, stream>>>(out1, ln2g, ln2b, h2);
    gemm_bt<64, 0><<<dim3(32, 64), 256, 0, stream>>>(h2, W1_b, b1, nullptr, nullptr, ff1, nullptr, nullptr, 8192, 4096, 1024, 1, 1);
    cvt_f32_bf16<<<2048, 256, 0, stream>>>(W2, W2_b, 4 * 1024 * 1024);
    gemm_bt<128, 0><<<dim3(8, 64), 256, 0, stream>>>(ff1, W2_b, b2, nullptr, out1, nullptr, out, nullptr, 8192, 1024, 4096, 1, 1);
  }
}